// Round 5
// baseline (495.730 us; speedup 1.0000x reference)
//
#include <hip/hip_runtime.h>
#include <hip/hip_bf16.h>

#define BB   256
#define NN   2207
#define MM   16
#define EE   16777216
#define CC1  12
#define CC2  4
#define HH1  256
#define HH2  64
#define KK1  (CC2*NN)          /* 8828 */
#define LN_EPS 1e-5f
#define BN_SCALE 0.9999950000374997f   /* 1/sqrt(1+1e-5) */
#define NBK  256               /* buckets == samples */
#define CAP  68096             /* per-bucket capacity; mean 65536, ~10 sigma headroom */
#define MAGIC 1946067ull       /* ceil(2^32/2207), exact for d < 564992 */
#define EPB  4096              /* edges per bin block */
#define TPB  512
#define EPT  (EPB/TPB)         /* 8 edges per thread */
#define GPAD 8                 /* glen stride in uints: 32B = one MALL granule */

static __device__ __forceinline__ unsigned bucket_of(int d) {
    return (unsigned)(((unsigned long long)(unsigned)d * MAGIC) >> 32);
}

// ============ PASS 1: counting sort, packed state, padded reserve counters ============
__global__ __launch_bounds__(TPB, 8)
void k_bin4(const int* __restrict__ src, const int* __restrict__ dst,
            const float* __restrict__ ew, const float* __restrict__ x,
            uint2* __restrict__ pairs, unsigned int* __restrict__ glen)
{
    __shared__ uint2        pl[EPB];            // 32 KB sorted (key, val) records
    __shared__ unsigned int hist[NBK], start[NBK], baseg[NBK];
    __shared__ unsigned int wtot[4];

    const int t = threadIdx.x;
    if (t < NBK) hist[t] = 0;
    __syncthreads();

    const int i4base = blockIdx.x * (EPB/4);

    // single pass: load edge, gather x (L2-hot), rank via one atomic per edge.
    // pk packs bucket(8b) | rank(12b) | dst_local(12b) -> 2 VGPRs/edge total.
    unsigned pk[EPT];
    float    pv[EPT];
    #pragma unroll
    for (int q = 0; q < EPT/4; ++q) {
        int i4 = i4base + q*TPB + t;
        int4   s4 = reinterpret_cast<const int4*>(src)[i4];
        int4   d4 = reinterpret_cast<const int4*>(dst)[i4];
        float4 w4 = reinterpret_cast<const float4*>(ew)[i4];
        {
            unsigned b_ = bucket_of(d4.x);
            unsigned r_ = atomicAdd(&hist[b_], 1u);
            pk[q*4+0] = (b_ << 24) | (r_ << 12) | (unsigned)(d4.x - (int)(b_*NN));
            pv[q*4+0] = x[s4.x] * w4.x;
        }
        {
            unsigned b_ = bucket_of(d4.y);
            unsigned r_ = atomicAdd(&hist[b_], 1u);
            pk[q*4+1] = (b_ << 24) | (r_ << 12) | (unsigned)(d4.y - (int)(b_*NN));
            pv[q*4+1] = x[s4.y] * w4.y;
        }
        {
            unsigned b_ = bucket_of(d4.z);
            unsigned r_ = atomicAdd(&hist[b_], 1u);
            pk[q*4+2] = (b_ << 24) | (r_ << 12) | (unsigned)(d4.z - (int)(b_*NN));
            pv[q*4+2] = x[s4.z] * w4.z;
        }
        {
            unsigned b_ = bucket_of(d4.w);
            unsigned r_ = atomicAdd(&hist[b_], 1u);
            pk[q*4+3] = (b_ << 24) | (r_ << 12) | (unsigned)(d4.w - (int)(b_*NN));
            pv[q*4+3] = x[s4.w] * w4.w;
        }
    }
    __syncthreads();

    // exclusive prefix scan of hist[256] (4 waves of 64)
    if (t < NBK) {
        unsigned h = hist[t], v = h;
        #pragma unroll
        for (int off = 1; off < 64; off <<= 1) {
            unsigned u = __shfl_up(v, off);
            if ((t & 63) >= off) v += u;
        }
        start[t] = v - h;
        if ((t & 63) == 63) wtot[t >> 6] = v;
    }
    __syncthreads();
    if (t < NBK) {
        const int w = t >> 6;
        unsigned wo = 0;
        if (w > 0) wo += wtot[0];
        if (w > 1) wo += wtot[1];
        if (w > 2) wo += wtot[2];
        start[t] += wo;
    }
    __syncthreads();

    // waves 0-3 reserve global space (padded counters -> parallel atomic queues)
    // while waves 4-7 proceed directly to the scatter below.
    if (t < NBK) {
        int j = (t + (blockIdx.x << 2)) & (NBK - 1);   // stagger reserve addresses
        baseg[j] = atomicAdd(&glen[j*GPAD], hist[j]);
    }

    // scatter into sorted LDS positions
    #pragma unroll
    for (int e = 0; e < EPT; ++e) {
        unsigned b_ = pk[e] >> 24;
        unsigned r_ = (pk[e] >> 12) & 0xFFFu;
        pl[start[b_] + r_] = make_uint2((b_ << 16) | (pk[e] & 0xFFFu),
                                        __float_as_uint(pv[e]));
    }
    __syncthreads();

    // coalesced flush: consecutive lanes write consecutive slots of each bucket run
    #pragma unroll
    for (int q = 0; q < EPT; ++q) {
        int i = q*TPB + t;
        uint2 r = pl[i];
        unsigned j = r.x >> 16;
        unsigned g = baseg[j] + ((unsigned)i - start[j]);
        if (g < CAP) pairs[(size_t)j*CAP + g] = make_uint2(r.x & 0xFFFFu, r.y);
    }
}

// ====== PASS 2 fused: LDS scatter-accumulate + relu/LN/conv1/bn/conv2/bn ======
#define STPB 1024
__global__ __launch_bounds__(STPB)
void k_sample_fused(const float* __restrict__ x,
              const uint2* __restrict__ pairs, const unsigned int* __restrict__ glen,
              const float* __restrict__ w_root, const float* __restrict__ w_rel,
              const float* __restrict__ b_rel,
              const float* __restrict__ ln_g, const float* __restrict__ ln_b,
              const float* __restrict__ gc1_w, const float* __restrict__ gc1_b,
              const float* __restrict__ bn1_g, const float* __restrict__ bn1_b,
              const float* __restrict__ gc2_w, const float* __restrict__ gc2_b,
              const float* __restrict__ bn2_g, const float* __restrict__ bn2_b,
              float* __restrict__ z)
{
    __shared__ float xs[NN], acc[NN];
    __shared__ float gw1[CC1*MM], gb1[CC1], sb1[CC1], tb1[CC1];
    __shared__ float gw2[CC2*CC1], gb2[CC2], sb2[CC2], tb2[CC2];
    __shared__ float redS[16], redQ[16];
    __shared__ float s_mu, s_rs;

    const int b = blockIdx.x, t = threadIdx.x;
    const float* xb = x + b*NN;
    for (int n = t; n < NN; n += STPB) { xs[n] = xb[n]; acc[n] = 0.f; }
    if (t < CC1*MM) gw1[t] = gc1_w[t];
    if (t >= 192 && t < 192+CC1) { int o = t-192; gb1[o]=gc1_b[o]; sb1[o]=BN_SCALE*bn1_g[o]; tb1[o]=bn1_b[o]; }
    if (t >= 208 && t < 208+CC2*CC1) gw2[t-208] = gc2_w[t-208];
    if (t >= 240 && t < 240+CC2) { int p=t-240; gb2[p]=gc2_b[p]; sb2[p]=BN_SCALE*bn2_g[p]; tb2[p]=bn2_b[p]; }

    float wr[MM], br[MM], wo[MM];
    #pragma unroll
    for (int m = 0; m < MM; ++m) { wr[m]=w_rel[m]; br[m]=b_rel[m]; wo[m]=w_root[m]; }
    __syncthreads();

    // replay this sample's bucket: 16B streaming reads + LDS atomics
    const unsigned len = min(glen[b*GPAD], (unsigned)CAP);
    const uint2* pp = pairs + (size_t)b*CAP;
    const uint4* pp4 = reinterpret_cast<const uint4*>(pp);
    const unsigned len2 = len >> 1;
    for (unsigned e = t; e < len2; e += STPB) {
        uint4 pr = pp4[e];
        atomicAdd(&acc[pr.x], __uint_as_float(pr.y));
        atomicAdd(&acc[pr.z], __uint_as_float(pr.w));
    }
    if (t == 0 && (len & 1u)) {
        uint2 pr = pp[len - 1];
        atomicAdd(&acc[pr.x], __uint_as_float(pr.y));
    }
    __syncthreads();

    // LN statistics over (N, M)
    float S = 0.f, Q = 0.f;
    for (int n = t; n < NN; n += STPB) {
        float a = acc[n], xv = xs[n];
        #pragma unroll
        for (int m = 0; m < MM; ++m) {
            float h = fmaxf(fmaf(a, wr[m], fmaf(xv, wo[m], br[m])), 0.f);
            S += h; Q += h*h;
        }
    }
    #pragma unroll
    for (int off = 32; off; off >>= 1) { S += __shfl_down(S, off); Q += __shfl_down(Q, off); }
    if ((t & 63) == 0) { redS[t>>6] = S; redQ[t>>6] = Q; }
    __syncthreads();
    if (t == 0) {
        float SS = 0.f, QQ = 0.f;
        #pragma unroll
        for (int i = 0; i < 16; ++i) { SS += redS[i]; QQ += redQ[i]; }
        const float inv = 1.f / (float)(NN*MM);
        float mu = SS * inv;
        float var = QQ * inv - mu*mu;
        s_mu = mu; s_rs = rsqrtf(var + LN_EPS);
    }
    __syncthreads();
    const float mu = s_mu, rs = s_rs;

    float* zb = z + (size_t)b * KK1;
    for (int n = t; n < NN; n += STPB) {
        float a = acc[n], xv = xs[n];
        float hn[MM];
        const float4* g4  = reinterpret_cast<const float4*>(ln_g + n*MM);
        const float4* be4 = reinterpret_cast<const float4*>(ln_b + n*MM);
        #pragma unroll
        for (int q = 0; q < 4; ++q) {
            float4 g = g4[q], be = be4[q];
            float gg[4]  = {g.x, g.y, g.z, g.w};
            float bb_[4] = {be.x, be.y, be.z, be.w};
            #pragma unroll
            for (int j = 0; j < 4; ++j) {
                int m = q*4 + j;
                float h = fmaxf(fmaf(a, wr[m], fmaf(xv, wo[m], br[m])), 0.f);
                hn[m] = (h - mu) * rs * gg[j] + bb_[j];
            }
        }
        float y1[CC1];
        #pragma unroll
        for (int o = 0; o < CC1; ++o) {
            float a1 = gb1[o];
            #pragma unroll
            for (int m = 0; m < MM; ++m) a1 = fmaf(gw1[o*MM+m], hn[m], a1);
            y1[o] = fmaxf(a1, 0.f) * sb1[o] + tb1[o];
        }
        #pragma unroll
        for (int p = 0; p < CC2; ++p) {
            float a2 = gb2[p];
            #pragma unroll
            for (int o = 0; o < CC1; ++o) a2 = fmaf(gw2[p*CC1+o], y1[o], a2);
            zb[p*NN + n] = fmaxf(a2, 0.f) * sb2[p] + tb2[p];
        }
    }
}

// ------------- FC1 GEMM: split-K partials (no atomics) -------------
#define GK_CHUNK 288   /* grid.z = 31; 31*288 = 8928 >= 8828 */
__global__ __launch_bounds__(256)
void k_fc1_part(const float* __restrict__ z, const float* __restrict__ W1,
                float* __restrict__ out1_part)
{
    __shared__ float zs[64*36];
    __shared__ float ws_[32*68];
    const int bt = blockIdx.x, jt = blockIdx.y, ks = blockIdx.z;
    const int t = threadIdx.x;
    const int tb = t >> 4, tj = t & 15;
    const int k0 = ks * GK_CHUNK;
    const int kend = min(k0 + GK_CHUNK, KK1);
    float acc[4][4] = {};
    const int zrow = t >> 2, zcol = (t & 3) * 8;
    const int wrow = t >> 3, wcol = (t & 7) * 8;

    for (int kc = k0; kc < kend; kc += 32) {
        const float* zsrc = z + (size_t)(bt*64 + zrow)*KK1 + kc + zcol;
        #pragma unroll
        for (int q = 0; q < 2; ++q) {
            int k = kc + zcol + q*4;
            float4 v;
            if (k + 3 < kend) v = *reinterpret_cast<const float4*>(zsrc + q*4);
            else {
                v.x = (k+0 < kend) ? zsrc[q*4+0] : 0.f;
                v.y = (k+1 < kend) ? zsrc[q*4+1] : 0.f;
                v.z = (k+2 < kend) ? zsrc[q*4+2] : 0.f;
                v.w = (k+3 < kend) ? zsrc[q*4+3] : 0.f;
            }
            *reinterpret_cast<float4*>(&zs[zrow*36 + zcol + q*4]) = v;
        }
        {
            int k = kc + wrow;
            const float* wsrc = W1 + (size_t)k*HH1 + jt*64 + wcol;
            #pragma unroll
            for (int q = 0; q < 2; ++q) {
                float4 v;
                if (k < kend) v = *reinterpret_cast<const float4*>(wsrc + q*4);
                else v = float4{0.f,0.f,0.f,0.f};
                *reinterpret_cast<float4*>(&ws_[wrow*68 + wcol + q*4]) = v;
            }
        }
        __syncthreads();
        #pragma unroll
        for (int kk = 0; kk < 32; ++kk) {
            float4 w4 = *reinterpret_cast<const float4*>(&ws_[kk*68 + tj*4]);
            float zv[4], wv[4] = {w4.x, w4.y, w4.z, w4.w};
            #pragma unroll
            for (int ib = 0; ib < 4; ++ib) zv[ib] = zs[(tb*4+ib)*36 + kk];
            #pragma unroll
            for (int ib = 0; ib < 4; ++ib)
                #pragma unroll
                for (int ij = 0; ij < 4; ++ij)
                    acc[ib][ij] = fmaf(zv[ib], wv[ij], acc[ib][ij]);
        }
        __syncthreads();
    }
    #pragma unroll
    for (int ib = 0; ib < 4; ++ib) {
        int row = bt*64 + tb*4 + ib;
        float4 v = make_float4(acc[ib][0], acc[ib][1], acc[ib][2], acc[ib][3]);
        *reinterpret_cast<float4*>(
            &out1_part[((size_t)ks*256 + row)*HH1 + jt*64 + tj*4]) = v;
    }
}

// ------------- tail: sum partials -> bn-relu -> FC2 -> bn-relu -> dot -------------
__global__ __launch_bounds__(256)
void k_tail_part(const float* __restrict__ out1_part,
            const float* __restrict__ fc_b1, const float* __restrict__ fbn1_g,
            const float* __restrict__ fbn1_b,
            const float* __restrict__ W2, const float* __restrict__ fc_b2,
            const float* __restrict__ fbn2_g, const float* __restrict__ fbn2_b,
            const float* __restrict__ fc1_w, const float* __restrict__ fc1_b,
            float* __restrict__ out)
{
    __shared__ float o1s[HH1];
    const int b = blockIdx.x, t = threadIdx.x;
    float raw = fc_b1[t];
    #pragma unroll 4
    for (int ks = 0; ks < 31; ++ks)
        raw += out1_part[((size_t)ks*256 + b)*HH1 + t];
    o1s[t] = fmaxf(raw * (BN_SCALE * fbn1_g[t]) + fbn1_b[t], 0.f);
    __syncthreads();
    if (t < HH2) {
        float acc = fc_b2[t];
        #pragma unroll 4
        for (int j = 0; j < HH1; ++j) acc = fmaf(o1s[j], W2[j*HH2 + t], acc);
        float v2 = fmaxf(acc * (BN_SCALE * fbn2_g[t]) + fbn2_b[t], 0.f);
        float c = v2 * fc1_w[t];
        #pragma unroll
        for (int off = 32; off; off >>= 1) c += __shfl_down(c, off);
        if (t == 0) out[b] = c + fc1_b[0];
    }
}

// =================== fallback path (round-1, proven; used if ws too small) ===================
__global__ __launch_bounds__(256)
void k_edge(const int* __restrict__ src, const int* __restrict__ dst,
            const float* __restrict__ ew, const float* __restrict__ x,
            float* __restrict__ agg)
{
    int i = blockIdx.x * 256 + threadIdx.x;
    const int4   s4 = reinterpret_cast<const int4*>(src)[i];
    const int4   d4 = reinterpret_cast<const int4*>(dst)[i];
    const float4 w4 = reinterpret_cast<const float4*>(ew)[i];
    unsafeAtomicAdd(&agg[d4.x], x[s4.x] * w4.x);
    unsafeAtomicAdd(&agg[d4.y], x[s4.y] * w4.y);
    unsafeAtomicAdd(&agg[d4.z], x[s4.z] * w4.z);
    unsafeAtomicAdd(&agg[d4.w], x[s4.w] * w4.w);
}

__global__ __launch_bounds__(256)
void k_sample(const float* __restrict__ x, const float* __restrict__ agg,
              const float* __restrict__ w_root, const float* __restrict__ w_rel,
              const float* __restrict__ b_rel,
              const float* __restrict__ ln_g, const float* __restrict__ ln_b,
              const float* __restrict__ gc1_w, const float* __restrict__ gc1_b,
              const float* __restrict__ bn1_g, const float* __restrict__ bn1_b,
              const float* __restrict__ gc2_w, const float* __restrict__ gc2_b,
              const float* __restrict__ bn2_g, const float* __restrict__ bn2_b,
              float* __restrict__ z)
{
    __shared__ float xs[NN], as[NN];
    __shared__ float gw1[CC1*MM], gb1[CC1], sb1[CC1], tb1[CC1];
    __shared__ float gw2[CC2*CC1], gb2[CC2], sb2[CC2], tb2[CC2];
    __shared__ float redS[4], redQ[4];
    __shared__ float s_mu, s_rs;

    const int b = blockIdx.x, t = threadIdx.x;
    const float* xb = x + b*NN;
    const float* ab = agg + b*NN;
    for (int n = t; n < NN; n += 256) { xs[n] = xb[n]; as[n] = ab[n]; }
    if (t < CC1*MM) gw1[t] = gc1_w[t];
    if (t >= 192 && t < 192+CC1) { int o = t-192; gb1[o]=gc1_b[o]; sb1[o]=BN_SCALE*bn1_g[o]; tb1[o]=bn1_b[o]; }
    if (t >= 208 && t < 208+CC2*CC1) gw2[t-208] = gc2_w[t-208];
    if (t >= 240 && t < 240+CC2) { int p=t-240; gb2[p]=gc2_b[p]; sb2[p]=BN_SCALE*bn2_g[p]; tb2[p]=bn2_b[p]; }

    float wr[MM], br[MM], wo[MM];
    #pragma unroll
    for (int m = 0; m < MM; ++m) { wr[m]=w_rel[m]; br[m]=b_rel[m]; wo[m]=w_root[m]; }
    __syncthreads();

    float S = 0.f, Q = 0.f;
    for (int n = t; n < NN; n += 256) {
        float a = as[n], xv = xs[n];
        #pragma unroll
        for (int m = 0; m < MM; ++m) {
            float h = fmaxf(fmaf(a, wr[m], fmaf(xv, wo[m], br[m])), 0.f);
            S += h; Q += h*h;
        }
    }
    #pragma unroll
    for (int off = 32; off; off >>= 1) { S += __shfl_down(S, off); Q += __shfl_down(Q, off); }
    if ((t & 63) == 0) { redS[t>>6] = S; redQ[t>>6] = Q; }
    __syncthreads();
    if (t == 0) {
        float SS = redS[0]+redS[1]+redS[2]+redS[3];
        float QQ = redQ[0]+redQ[1]+redQ[2]+redQ[3];
        const float inv = 1.f / (float)(NN*MM);
        float mu = SS * inv;
        float var = QQ * inv - mu*mu;
        s_mu = mu; s_rs = rsqrtf(var + LN_EPS);
    }
    __syncthreads();
    const float mu = s_mu, rs = s_rs;

    float* zb = z + (size_t)b * KK1;
    for (int n = t; n < NN; n += 256) {
        float a = as[n], xv = xs[n];
        float hn[MM];
        const float4* g4  = reinterpret_cast<const float4*>(ln_g + n*MM);
        const float4* be4 = reinterpret_cast<const float4*>(ln_b + n*MM);
        #pragma unroll
        for (int q = 0; q < 4; ++q) {
            float4 g = g4[q], be = be4[q];
            float gg[4]  = {g.x, g.y, g.z, g.w};
            float bb_[4] = {be.x, be.y, be.z, be.w};
            #pragma unroll
            for (int j = 0; j < 4; ++j) {
                int m = q*4 + j;
                float h = fmaxf(fmaf(a, wr[m], fmaf(xv, wo[m], br[m])), 0.f);
                hn[m] = (h - mu) * rs * gg[j] + bb_[j];
            }
        }
        float y1[CC1];
        #pragma unroll
        for (int o = 0; o < CC1; ++o) {
            float a1 = gb1[o];
            #pragma unroll
            for (int m = 0; m < MM; ++m) a1 = fmaf(gw1[o*MM+m], hn[m], a1);
            y1[o] = fmaxf(a1, 0.f) * sb1[o] + tb1[o];
        }
        #pragma unroll
        for (int p = 0; p < CC2; ++p) {
            float a2 = gb2[p];
            #pragma unroll
            for (int o = 0; o < CC1; ++o) a2 = fmaf(gw2[p*CC1+o], y1[o], a2);
            zb[p*NN + n] = fmaxf(a2, 0.f) * sb2[p] + tb2[p];
        }
    }
}

__global__ __launch_bounds__(256)
void k_fc1(const float* __restrict__ z, const float* __restrict__ W1,
           float* __restrict__ out1_raw)
{
    __shared__ float zs[64*36];
    __shared__ float ws_[32*68];
    const int bt = blockIdx.x, jt = blockIdx.y, ks = blockIdx.z;
    const int t = threadIdx.x;
    const int tb = t >> 4, tj = t & 15;
    const int k0 = ks * GK_CHUNK;
    const int kend = min(k0 + GK_CHUNK, KK1);
    float acc[4][4] = {};
    const int zrow = t >> 2, zcol = (t & 3) * 8;
    const int wrow = t >> 3, wcol = (t & 7) * 8;

    for (int kc = k0; kc < kend; kc += 32) {
        const float* zsrc = z + (size_t)(bt*64 + zrow)*KK1 + kc + zcol;
        #pragma unroll
        for (int q = 0; q < 2; ++q) {
            int k = kc + zcol + q*4;
            float4 v;
            if (k + 3 < kend) v = *reinterpret_cast<const float4*>(zsrc + q*4);
            else {
                v.x = (k+0 < kend) ? zsrc[q*4+0] : 0.f;
                v.y = (k+1 < kend) ? zsrc[q*4+1] : 0.f;
                v.z = (k+2 < kend) ? zsrc[q*4+2] : 0.f;
                v.w = (k+3 < kend) ? zsrc[q*4+3] : 0.f;
            }
            *reinterpret_cast<float4*>(&zs[zrow*36 + zcol + q*4]) = v;
        }
        {
            int k = kc + wrow;
            const float* wsrc = W1 + (size_t)k*HH1 + jt*64 + wcol;
            #pragma unroll
            for (int q = 0; q < 2; ++q) {
                float4 v;
                if (k < kend) v = *reinterpret_cast<const float4*>(wsrc + q*4);
                else v = float4{0.f,0.f,0.f,0.f};
                *reinterpret_cast<float4*>(&ws_[wrow*68 + wcol + q*4]) = v;
            }
        }
        __syncthreads();
        #pragma unroll
        for (int kk = 0; kk < 32; ++kk) {
            float4 w4 = *reinterpret_cast<const float4*>(&ws_[kk*68 + tj*4]);
            float zv[4], wv[4] = {w4.x, w4.y, w4.z, w4.w};
            #pragma unroll
            for (int ib = 0; ib < 4; ++ib) zv[ib] = zs[(tb*4+ib)*36 + kk];
            #pragma unroll
            for (int ib = 0; ib < 4; ++ib)
                #pragma unroll
                for (int ij = 0; ij < 4; ++ij)
                    acc[ib][ij] = fmaf(zv[ib], wv[ij], acc[ib][ij]);
        }
        __syncthreads();
    }
    #pragma unroll
    for (int ib = 0; ib < 4; ++ib) {
        int row = bt*64 + tb*4 + ib;
        #pragma unroll
        for (int ij = 0; ij < 4; ++ij)
            unsafeAtomicAdd(&out1_raw[row*HH1 + jt*64 + tj*4 + ij], acc[ib][ij]);
    }
}

__global__ __launch_bounds__(256)
void k_tail(const float* __restrict__ out1_raw,
            const float* __restrict__ fc_b1, const float* __restrict__ fbn1_g,
            const float* __restrict__ fbn1_b,
            const float* __restrict__ W2, const float* __restrict__ fc_b2,
            const float* __restrict__ fbn2_g, const float* __restrict__ fbn2_b,
            const float* __restrict__ fc1_w, const float* __restrict__ fc1_b,
            float* __restrict__ out)
{
    __shared__ float o1s[HH1];
    const int b = blockIdx.x, t = threadIdx.x;
    float raw = out1_raw[b*HH1 + t] + fc_b1[t];
    o1s[t] = fmaxf(raw * (BN_SCALE * fbn1_g[t]) + fbn1_b[t], 0.f);
    __syncthreads();
    if (t < HH2) {
        float acc = fc_b2[t];
        #pragma unroll 4
        for (int j = 0; j < HH1; ++j) acc = fmaf(o1s[j], W2[j*HH2 + t], acc);
        float v2 = fmaxf(acc * (BN_SCALE * fbn2_g[t]) + fbn2_b[t], 0.f);
        float c = v2 * fc1_w[t];
        #pragma unroll
        for (int off = 32; off; off >>= 1) c += __shfl_down(c, off);
        if (t == 0) out[b] = c + fc1_b[0];
    }
}

extern "C" void kernel_launch(void* const* d_in, const int* in_sizes, int n_in,
                              void* d_out, int out_size, void* d_ws, size_t ws_size,
                              hipStream_t stream)
{
    const float* x      = (const float*)d_in[0];
    const int*   ei     = (const int*)  d_in[1];
    const float* ew     = (const float*)d_in[2];
    const float* w_root = (const float*)d_in[3];
    const float* w_rel  = (const float*)d_in[4];
    const float* b_rel  = (const float*)d_in[5];
    const float* ln_g   = (const float*)d_in[6];
    const float* ln_b   = (const float*)d_in[7];
    const float* gc1_w  = (const float*)d_in[8];
    const float* gc1_b  = (const float*)d_in[9];
    const float* bn1_g  = (const float*)d_in[10];
    const float* bn1_b  = (const float*)d_in[11];
    const float* gc2_w  = (const float*)d_in[12];
    const float* gc2_b  = (const float*)d_in[13];
    const float* bn2_g  = (const float*)d_in[14];
    const float* bn2_b  = (const float*)d_in[15];
    const float* fc_w1  = (const float*)d_in[16];
    const float* fc_b1  = (const float*)d_in[17];
    const float* fbn1_g = (const float*)d_in[18];
    const float* fbn1_b = (const float*)d_in[19];
    const float* fc_w2  = (const float*)d_in[20];
    const float* fc_b2  = (const float*)d_in[21];
    const float* fbn2_g = (const float*)d_in[22];
    const float* fbn2_b = (const float*)d_in[23];
    const float* fc1_w  = (const float*)d_in[24];
    const float* fc1_b  = (const float*)d_in[25];
    float* out = (float*)d_out;

    char* ws = (char*)d_ws;
    const size_t off_pairs = 0;                                   // 256*CAP*8 = 139,460,608
    const size_t off_glen  = off_pairs + (size_t)NBK*CAP*8;       // +8192 (padded counters)
    const size_t off_zbuf  = off_glen + (size_t)NBK*GPAD*4;       // +9,039,872
    const size_t off_op    = off_zbuf + (size_t)BB*KK1*4;         // +31*65536*4
    const size_t need      = off_op + (size_t)31*HH1*256*4;

    if (ws_size >= need) {
        uint2*        pairs = (uint2*)(ws + off_pairs);
        unsigned int* glen  = (unsigned int*)(ws + off_glen);
        float*        zbuf  = (float*)(ws + off_zbuf);
        float*        o1p   = (float*)(ws + off_op);

        hipMemsetAsync(glen, 0, (size_t)NBK*GPAD*4, stream);
        k_bin4<<<EE/EPB, TPB, 0, stream>>>(ei, ei + EE, ew, x, pairs, glen);
        k_sample_fused<<<BB, STPB, 0, stream>>>(x, pairs, glen,
                                         w_root, w_rel, b_rel, ln_g, ln_b,
                                         gc1_w, gc1_b, bn1_g, bn1_b,
                                         gc2_w, gc2_b, bn2_g, bn2_b, zbuf);
        k_fc1_part<<<dim3(4,4,31), 256, 0, stream>>>(zbuf, fc_w1, o1p);
        k_tail_part<<<BB, 256, 0, stream>>>(o1p, fc_b1, fbn1_g, fbn1_b,
                                       fc_w2, fc_b2, fbn2_g, fbn2_b,
                                       fc1_w, fc1_b, out);
    } else {
        // round-1 fallback (proven <= 11.6 MB ws)
        float* agg      = (float*)(ws);
        float* zbuf     = (float*)(ws + 2259968);
        float* out1_raw = (float*)(ws + 2259968 + 9039872);

        hipMemsetAsync(agg,      0, (size_t)BB*NN*sizeof(float),  stream);
        hipMemsetAsync(out1_raw, 0, (size_t)BB*HH1*sizeof(float), stream);

        k_edge<<<EE/4/256, 256, 0, stream>>>(ei, ei + EE, ew, x, agg);
        k_sample<<<BB, 256, 0, stream>>>(x, agg, w_root, w_rel, b_rel, ln_g, ln_b,
                                         gc1_w, gc1_b, bn1_g, bn1_b,
                                         gc2_w, gc2_b, bn2_g, bn2_b, zbuf);
        k_fc1<<<dim3(4,4,31), 256, 0, stream>>>(zbuf, fc_w1, out1_raw);
        k_tail<<<BB, 256, 0, stream>>>(out1_raw, fc_b1, fbn1_g, fbn1_b,
                                       fc_w2, fc_b2, fbn2_g, fbn2_b,
                                       fc1_w, fc1_b, out);
    }
}

// Round 6
// 391.140 us; speedup vs baseline: 1.2674x; 1.2674x over previous
//
#include <hip/hip_runtime.h>
#include <hip/hip_bf16.h>

#define BB   256
#define NN   2207
#define MM   16
#define EE   16777216
#define CC1  12
#define CC2  4
#define HH1  256
#define HH2  64
#define KK1  (CC2*NN)          /* 8828 */
#define LN_EPS 1e-5f
#define BN_SCALE 0.9999950000374997f   /* 1/sqrt(1+1e-5) */
#define NBK  256               /* buckets == samples */
#define CAP  68096             /* per-bucket capacity; mean 65536, ~10 sigma headroom */
#define MAGIC 1946067ull       /* ceil(2^32/2207), exact for d < 564992 */
#define EPB  4096              /* edges per bin block */
#define TPB  512
#define EPT  (EPB/TPB)         /* 8 edges per thread */
#define NBLK (EE/EPB)          /* 4096 bin blocks */

static __device__ __forceinline__ unsigned bucket_of(int d) {
    return (unsigned)(((unsigned long long)(unsigned)d * MAGIC) >> 32);
}

// ============ PASS 1a: per-block histogram (no returns, tiny LDS) ============
__global__ __launch_bounds__(TPB)
void k_cnt(const int* __restrict__ dst, unsigned int* __restrict__ cnt)
{
    __shared__ unsigned int hist[NBK];
    const int t = threadIdx.x;
    if (t < NBK) hist[t] = 0;
    __syncthreads();
    const int i4base = blockIdx.x * (EPB/4);
    #pragma unroll
    for (int q = 0; q < EPT/4; ++q) {
        int4 d4 = reinterpret_cast<const int4*>(dst)[i4base + q*TPB + t];
        atomicAdd(&hist[bucket_of(d4.x)], 1u);   // fire-and-forget
        atomicAdd(&hist[bucket_of(d4.y)], 1u);
        atomicAdd(&hist[bucket_of(d4.z)], 1u);
        atomicAdd(&hist[bucket_of(d4.w)], 1u);
    }
    __syncthreads();
    if (t < NBK) cnt[blockIdx.x * NBK + t] = hist[t];
}

// ============ PASS 1b: per-bucket exclusive scan over blocks (no atomics) ============
__global__ __launch_bounds__(256)
void k_scan(const unsigned int* __restrict__ cnt,
            unsigned int* __restrict__ base, unsigned int* __restrict__ lens)
{
    __shared__ unsigned int wsum[4];
    const int j = blockIdx.x, t = threadIdx.x, w = t >> 6;
    unsigned run = 0;
    for (int c = 0; c < NBLK/256; ++c) {
        int blk = c*256 + t;
        unsigned v = cnt[blk * NBK + j];
        unsigned s = v;
        #pragma unroll
        for (int off = 1; off < 64; off <<= 1) {
            unsigned u = __shfl_up(s, off);
            if ((t & 63) >= off) s += u;
        }
        if ((t & 63) == 63) wsum[w] = s;
        __syncthreads();
        unsigned wo = 0, tot = 0;
        #pragma unroll
        for (int k = 0; k < 4; ++k) { unsigned x = wsum[k]; tot += x; if (k < w) wo += x; }
        base[blk * NBK + j] = run + wo + (s - v);
        run += tot;
        __syncthreads();
    }
    if (t == 0) lens[j] = run;
}

// ============ PASS 1c: LDS counting sort -> flush to precomputed bases ============
__global__ __launch_bounds__(TPB, 8)
void k_place(const int* __restrict__ src, const int* __restrict__ dst,
             const float* __restrict__ ew, const float* __restrict__ x,
             const unsigned int* __restrict__ base,
             uint2* __restrict__ pairs)
{
    __shared__ uint2        pl[EPB];            // 32 KB sorted (key, val) records
    __shared__ unsigned int hist[NBK], start[NBK], baseg[NBK];
    __shared__ unsigned int wtot[4];

    const int t = threadIdx.x;
    if (t < NBK) { hist[t] = 0; baseg[t] = base[blockIdx.x * NBK + t]; }
    __syncthreads();

    const int i4base = blockIdx.x * (EPB/4);
    unsigned pk[EPT];
    float    pv[EPT];
    #pragma unroll
    for (int q = 0; q < EPT/4; ++q) {
        int i4 = i4base + q*TPB + t;
        int4   s4 = reinterpret_cast<const int4*>(src)[i4];
        int4   d4 = reinterpret_cast<const int4*>(dst)[i4];
        float4 w4 = reinterpret_cast<const float4*>(ew)[i4];
        {
            unsigned b_ = bucket_of(d4.x);
            unsigned r_ = atomicAdd(&hist[b_], 1u);
            pk[q*4+0] = (b_ << 24) | (r_ << 12) | (unsigned)(d4.x - (int)(b_*NN));
            pv[q*4+0] = x[s4.x] * w4.x;
        }
        {
            unsigned b_ = bucket_of(d4.y);
            unsigned r_ = atomicAdd(&hist[b_], 1u);
            pk[q*4+1] = (b_ << 24) | (r_ << 12) | (unsigned)(d4.y - (int)(b_*NN));
            pv[q*4+1] = x[s4.y] * w4.y;
        }
        {
            unsigned b_ = bucket_of(d4.z);
            unsigned r_ = atomicAdd(&hist[b_], 1u);
            pk[q*4+2] = (b_ << 24) | (r_ << 12) | (unsigned)(d4.z - (int)(b_*NN));
            pv[q*4+2] = x[s4.z] * w4.z;
        }
        {
            unsigned b_ = bucket_of(d4.w);
            unsigned r_ = atomicAdd(&hist[b_], 1u);
            pk[q*4+3] = (b_ << 24) | (r_ << 12) | (unsigned)(d4.w - (int)(b_*NN));
            pv[q*4+3] = x[s4.w] * w4.w;
        }
    }
    __syncthreads();

    // exclusive prefix scan of hist[256] (4 waves of 64)
    if (t < NBK) {
        unsigned h = hist[t], v = h;
        #pragma unroll
        for (int off = 1; off < 64; off <<= 1) {
            unsigned u = __shfl_up(v, off);
            if ((t & 63) >= off) v += u;
        }
        start[t] = v - h;
        if ((t & 63) == 63) wtot[t >> 6] = v;
    }
    __syncthreads();
    if (t < NBK) {
        const int w = t >> 6;
        unsigned wo = 0;
        if (w > 0) wo += wtot[0];
        if (w > 1) wo += wtot[1];
        if (w > 2) wo += wtot[2];
        start[t] += wo;
    }
    __syncthreads();

    // scatter into sorted LDS positions
    #pragma unroll
    for (int e = 0; e < EPT; ++e) {
        unsigned b_ = pk[e] >> 24;
        unsigned r_ = (pk[e] >> 12) & 0xFFFu;
        pl[start[b_] + r_] = make_uint2((b_ << 16) | (pk[e] & 0xFFFu),
                                        __float_as_uint(pv[e]));
    }
    __syncthreads();

    // coalesced flush: consecutive lanes write consecutive slots of each bucket run
    #pragma unroll
    for (int q = 0; q < EPT; ++q) {
        int i = q*TPB + t;
        uint2 r = pl[i];
        unsigned j = r.x >> 16;
        unsigned g = baseg[j] + ((unsigned)i - start[j]);
        if (g < CAP) pairs[(size_t)j*CAP + g] = make_uint2(r.x & 0xFFFFu, r.y);
    }
}

// ====== PASS 2 fused: LDS scatter-accumulate + relu/LN/conv1/bn/conv2/bn ======
__global__ __launch_bounds__(512)
void k_sample_fused(const float* __restrict__ x,
              const uint2* __restrict__ pairs, const unsigned int* __restrict__ lens,
              const float* __restrict__ w_root, const float* __restrict__ w_rel,
              const float* __restrict__ b_rel,
              const float* __restrict__ ln_g, const float* __restrict__ ln_b,
              const float* __restrict__ gc1_w, const float* __restrict__ gc1_b,
              const float* __restrict__ bn1_g, const float* __restrict__ bn1_b,
              const float* __restrict__ gc2_w, const float* __restrict__ gc2_b,
              const float* __restrict__ bn2_g, const float* __restrict__ bn2_b,
              float* __restrict__ z)
{
    __shared__ float xs[NN], acc[NN];
    __shared__ float gw1[CC1*MM], gb1[CC1], sb1[CC1], tb1[CC1];
    __shared__ float gw2[CC2*CC1], gb2[CC2], sb2[CC2], tb2[CC2];
    __shared__ float redS[8], redQ[8];
    __shared__ float s_mu, s_rs;

    const int b = blockIdx.x, t = threadIdx.x;
    const float* xb = x + b*NN;
    for (int n = t; n < NN; n += 512) { xs[n] = xb[n]; acc[n] = 0.f; }
    if (t < CC1*MM) gw1[t] = gc1_w[t];
    if (t >= 192 && t < 192+CC1) { int o = t-192; gb1[o]=gc1_b[o]; sb1[o]=BN_SCALE*bn1_g[o]; tb1[o]=bn1_b[o]; }
    if (t >= 208 && t < 208+CC2*CC1) gw2[t-208] = gc2_w[t-208];
    if (t >= 240 && t < 240+CC2) { int p=t-240; gb2[p]=gc2_b[p]; sb2[p]=BN_SCALE*bn2_g[p]; tb2[p]=bn2_b[p]; }

    float wr[MM], br[MM], wo[MM];
    #pragma unroll
    for (int m = 0; m < MM; ++m) { wr[m]=w_rel[m]; br[m]=b_rel[m]; wo[m]=w_root[m]; }
    __syncthreads();

    // replay this sample's bucket: 16B streaming reads (4 in flight) + LDS adds
    const unsigned len = min(lens[b], (unsigned)CAP);
    const uint2* pp = pairs + (size_t)b*CAP;
    const uint4* pp4 = reinterpret_cast<const uint4*>(pp);
    const unsigned n4 = len >> 1;
    unsigned e = t;
    for (; e + 3u*512u < n4; e += 4u*512u) {
        uint4 a0 = pp4[e];
        uint4 a1 = pp4[e + 512u];
        uint4 a2 = pp4[e + 1024u];
        uint4 a3 = pp4[e + 1536u];
        atomicAdd(&acc[a0.x], __uint_as_float(a0.y));
        atomicAdd(&acc[a0.z], __uint_as_float(a0.w));
        atomicAdd(&acc[a1.x], __uint_as_float(a1.y));
        atomicAdd(&acc[a1.z], __uint_as_float(a1.w));
        atomicAdd(&acc[a2.x], __uint_as_float(a2.y));
        atomicAdd(&acc[a2.z], __uint_as_float(a2.w));
        atomicAdd(&acc[a3.x], __uint_as_float(a3.y));
        atomicAdd(&acc[a3.z], __uint_as_float(a3.w));
    }
    for (; e < n4; e += 512u) {
        uint4 a0 = pp4[e];
        atomicAdd(&acc[a0.x], __uint_as_float(a0.y));
        atomicAdd(&acc[a0.z], __uint_as_float(a0.w));
    }
    if (t == 0 && (len & 1u)) {
        uint2 pr = pp[len - 1];
        atomicAdd(&acc[pr.x], __uint_as_float(pr.y));
    }
    __syncthreads();

    // LN statistics over (N, M)
    float S = 0.f, Q = 0.f;
    for (int n = t; n < NN; n += 512) {
        float a = acc[n], xv = xs[n];
        #pragma unroll
        for (int m = 0; m < MM; ++m) {
            float h = fmaxf(fmaf(a, wr[m], fmaf(xv, wo[m], br[m])), 0.f);
            S += h; Q += h*h;
        }
    }
    #pragma unroll
    for (int off = 32; off; off >>= 1) { S += __shfl_down(S, off); Q += __shfl_down(Q, off); }
    if ((t & 63) == 0) { redS[t>>6] = S; redQ[t>>6] = Q; }
    __syncthreads();
    if (t == 0) {
        float SS = 0.f, QQ = 0.f;
        #pragma unroll
        for (int i = 0; i < 8; ++i) { SS += redS[i]; QQ += redQ[i]; }
        const float inv = 1.f / (float)(NN*MM);
        float mu = SS * inv;
        float var = QQ * inv - mu*mu;
        s_mu = mu; s_rs = rsqrtf(var + LN_EPS);
    }
    __syncthreads();
    const float mu = s_mu, rs = s_rs;

    float* zb = z + (size_t)b * KK1;
    for (int n = t; n < NN; n += 512) {
        float a = acc[n], xv = xs[n];
        float hn[MM];
        const float4* g4  = reinterpret_cast<const float4*>(ln_g + n*MM);
        const float4* be4 = reinterpret_cast<const float4*>(ln_b + n*MM);
        #pragma unroll
        for (int q = 0; q < 4; ++q) {
            float4 g = g4[q], be = be4[q];
            float gg[4]  = {g.x, g.y, g.z, g.w};
            float bb_[4] = {be.x, be.y, be.z, be.w};
            #pragma unroll
            for (int j = 0; j < 4; ++j) {
                int m = q*4 + j;
                float h = fmaxf(fmaf(a, wr[m], fmaf(xv, wo[m], br[m])), 0.f);
                hn[m] = (h - mu) * rs * gg[j] + bb_[j];
            }
        }
        float y1[CC1];
        #pragma unroll
        for (int o = 0; o < CC1; ++o) {
            float a1 = gb1[o];
            #pragma unroll
            for (int m = 0; m < MM; ++m) a1 = fmaf(gw1[o*MM+m], hn[m], a1);
            y1[o] = fmaxf(a1, 0.f) * sb1[o] + tb1[o];
        }
        #pragma unroll
        for (int p = 0; p < CC2; ++p) {
            float a2 = gb2[p];
            #pragma unroll
            for (int o = 0; o < CC1; ++o) a2 = fmaf(gw2[p*CC1+o], y1[o], a2);
            zb[p*NN + n] = fmaxf(a2, 0.f) * sb2[p] + tb2[p];
        }
    }
}

// ------------- FC1 GEMM: split-K partials (no atomics) -------------
#define GK_CHUNK 288   /* grid.z = 31; 31*288 = 8928 >= 8828 */
__global__ __launch_bounds__(256)
void k_fc1_part(const float* __restrict__ z, const float* __restrict__ W1,
                float* __restrict__ out1_part)
{
    __shared__ float zs[64*36];
    __shared__ float ws_[32*68];
    const int bt = blockIdx.x, jt = blockIdx.y, ks = blockIdx.z;
    const int t = threadIdx.x;
    const int tb = t >> 4, tj = t & 15;
    const int k0 = ks * GK_CHUNK;
    const int kend = min(k0 + GK_CHUNK, KK1);
    float acc[4][4] = {};
    const int zrow = t >> 2, zcol = (t & 3) * 8;
    const int wrow = t >> 3, wcol = (t & 7) * 8;

    for (int kc = k0; kc < kend; kc += 32) {
        const float* zsrc = z + (size_t)(bt*64 + zrow)*KK1 + kc + zcol;
        #pragma unroll
        for (int q = 0; q < 2; ++q) {
            int k = kc + zcol + q*4;
            float4 v;
            if (k + 3 < kend) v = *reinterpret_cast<const float4*>(zsrc + q*4);
            else {
                v.x = (k+0 < kend) ? zsrc[q*4+0] : 0.f;
                v.y = (k+1 < kend) ? zsrc[q*4+1] : 0.f;
                v.z = (k+2 < kend) ? zsrc[q*4+2] : 0.f;
                v.w = (k+3 < kend) ? zsrc[q*4+3] : 0.f;
            }
            *reinterpret_cast<float4*>(&zs[zrow*36 + zcol + q*4]) = v;
        }
        {
            int k = kc + wrow;
            const float* wsrc = W1 + (size_t)k*HH1 + jt*64 + wcol;
            #pragma unroll
            for (int q = 0; q < 2; ++q) {
                float4 v;
                if (k < kend) v = *reinterpret_cast<const float4*>(wsrc + q*4);
                else v = float4{0.f,0.f,0.f,0.f};
                *reinterpret_cast<float4*>(&ws_[wrow*68 + wcol + q*4]) = v;
            }
        }
        __syncthreads();
        #pragma unroll
        for (int kk = 0; kk < 32; ++kk) {
            float4 w4 = *reinterpret_cast<const float4*>(&ws_[kk*68 + tj*4]);
            float zv[4], wv[4] = {w4.x, w4.y, w4.z, w4.w};
            #pragma unroll
            for (int ib = 0; ib < 4; ++ib) zv[ib] = zs[(tb*4+ib)*36 + kk];
            #pragma unroll
            for (int ib = 0; ib < 4; ++ib)
                #pragma unroll
                for (int ij = 0; ij < 4; ++ij)
                    acc[ib][ij] = fmaf(zv[ib], wv[ij], acc[ib][ij]);
        }
        __syncthreads();
    }
    #pragma unroll
    for (int ib = 0; ib < 4; ++ib) {
        int row = bt*64 + tb*4 + ib;
        float4 v = make_float4(acc[ib][0], acc[ib][1], acc[ib][2], acc[ib][3]);
        *reinterpret_cast<float4*>(
            &out1_part[((size_t)ks*256 + row)*HH1 + jt*64 + tj*4]) = v;
    }
}

// ------------- tail: sum partials -> bn-relu -> FC2 -> bn-relu -> dot -------------
__global__ __launch_bounds__(256)
void k_tail_part(const float* __restrict__ out1_part,
            const float* __restrict__ fc_b1, const float* __restrict__ fbn1_g,
            const float* __restrict__ fbn1_b,
            const float* __restrict__ W2, const float* __restrict__ fc_b2,
            const float* __restrict__ fbn2_g, const float* __restrict__ fbn2_b,
            const float* __restrict__ fc1_w, const float* __restrict__ fc1_b,
            float* __restrict__ out)
{
    __shared__ float o1s[HH1];
    const int b = blockIdx.x, t = threadIdx.x;
    float raw = fc_b1[t];
    #pragma unroll 4
    for (int ks = 0; ks < 31; ++ks)
        raw += out1_part[((size_t)ks*256 + b)*HH1 + t];
    o1s[t] = fmaxf(raw * (BN_SCALE * fbn1_g[t]) + fbn1_b[t], 0.f);
    __syncthreads();
    if (t < HH2) {
        float acc = fc_b2[t];
        #pragma unroll 4
        for (int j = 0; j < HH1; ++j) acc = fmaf(o1s[j], W2[j*HH2 + t], acc);
        float v2 = fmaxf(acc * (BN_SCALE * fbn2_g[t]) + fbn2_b[t], 0.f);
        float c = v2 * fc1_w[t];
        #pragma unroll
        for (int off = 32; off; off >>= 1) c += __shfl_down(c, off);
        if (t == 0) out[b] = c + fc1_b[0];
    }
}

// =================== fallback path (round-1, proven; used if ws too small) ===================
__global__ __launch_bounds__(256)
void k_edge(const int* __restrict__ src, const int* __restrict__ dst,
            const float* __restrict__ ew, const float* __restrict__ x,
            float* __restrict__ agg)
{
    int i = blockIdx.x * 256 + threadIdx.x;
    const int4   s4 = reinterpret_cast<const int4*>(src)[i];
    const int4   d4 = reinterpret_cast<const int4*>(dst)[i];
    const float4 w4 = reinterpret_cast<const float4*>(ew)[i];
    unsafeAtomicAdd(&agg[d4.x], x[s4.x] * w4.x);
    unsafeAtomicAdd(&agg[d4.y], x[s4.y] * w4.y);
    unsafeAtomicAdd(&agg[d4.z], x[s4.z] * w4.z);
    unsafeAtomicAdd(&agg[d4.w], x[s4.w] * w4.w);
}

__global__ __launch_bounds__(256)
void k_sample(const float* __restrict__ x, const float* __restrict__ agg,
              const float* __restrict__ w_root, const float* __restrict__ w_rel,
              const float* __restrict__ b_rel,
              const float* __restrict__ ln_g, const float* __restrict__ ln_b,
              const float* __restrict__ gc1_w, const float* __restrict__ gc1_b,
              const float* __restrict__ bn1_g, const float* __restrict__ bn1_b,
              const float* __restrict__ gc2_w, const float* __restrict__ gc2_b,
              const float* __restrict__ bn2_g, const float* __restrict__ bn2_b,
              float* __restrict__ z)
{
    __shared__ float xs[NN], as[NN];
    __shared__ float gw1[CC1*MM], gb1[CC1], sb1[CC1], tb1[CC1];
    __shared__ float gw2[CC2*CC1], gb2[CC2], sb2[CC2], tb2[CC2];
    __shared__ float redS[4], redQ[4];
    __shared__ float s_mu, s_rs;

    const int b = blockIdx.x, t = threadIdx.x;
    const float* xb = x + b*NN;
    const float* ab = agg + b*NN;
    for (int n = t; n < NN; n += 256) { xs[n] = xb[n]; as[n] = ab[n]; }
    if (t < CC1*MM) gw1[t] = gc1_w[t];
    if (t >= 192 && t < 192+CC1) { int o = t-192; gb1[o]=gc1_b[o]; sb1[o]=BN_SCALE*bn1_g[o]; tb1[o]=bn1_b[o]; }
    if (t >= 208 && t < 208+CC2*CC1) gw2[t-208] = gc2_w[t-208];
    if (t >= 240 && t < 240+CC2) { int p=t-240; gb2[p]=gc2_b[p]; sb2[p]=BN_SCALE*bn2_g[p]; tb2[p]=bn2_b[p]; }

    float wr[MM], br[MM], wo[MM];
    #pragma unroll
    for (int m = 0; m < MM; ++m) { wr[m]=w_rel[m]; br[m]=b_rel[m]; wo[m]=w_root[m]; }
    __syncthreads();

    float S = 0.f, Q = 0.f;
    for (int n = t; n < NN; n += 256) {
        float a = as[n], xv = xs[n];
        #pragma unroll
        for (int m = 0; m < MM; ++m) {
            float h = fmaxf(fmaf(a, wr[m], fmaf(xv, wo[m], br[m])), 0.f);
            S += h; Q += h*h;
        }
    }
    #pragma unroll
    for (int off = 32; off; off >>= 1) { S += __shfl_down(S, off); Q += __shfl_down(Q, off); }
    if ((t & 63) == 0) { redS[t>>6] = S; redQ[t>>6] = Q; }
    __syncthreads();
    if (t == 0) {
        float SS = redS[0]+redS[1]+redS[2]+redS[3];
        float QQ = redQ[0]+redQ[1]+redQ[2]+redQ[3];
        const float inv = 1.f / (float)(NN*MM);
        float mu = SS * inv;
        float var = QQ * inv - mu*mu;
        s_mu = mu; s_rs = rsqrtf(var + LN_EPS);
    }
    __syncthreads();
    const float mu = s_mu, rs = s_rs;

    float* zb = z + (size_t)b * KK1;
    for (int n = t; n < NN; n += 256) {
        float a = as[n], xv = xs[n];
        float hn[MM];
        const float4* g4  = reinterpret_cast<const float4*>(ln_g + n*MM);
        const float4* be4 = reinterpret_cast<const float4*>(ln_b + n*MM);
        #pragma unroll
        for (int q = 0; q < 4; ++q) {
            float4 g = g4[q], be = be4[q];
            float gg[4]  = {g.x, g.y, g.z, g.w};
            float bb_[4] = {be.x, be.y, be.z, be.w};
            #pragma unroll
            for (int j = 0; j < 4; ++j) {
                int m = q*4 + j;
                float h = fmaxf(fmaf(a, wr[m], fmaf(xv, wo[m], br[m])), 0.f);
                hn[m] = (h - mu) * rs * gg[j] + bb_[j];
            }
        }
        float y1[CC1];
        #pragma unroll
        for (int o = 0; o < CC1; ++o) {
            float a1 = gb1[o];
            #pragma unroll
            for (int m = 0; m < MM; ++m) a1 = fmaf(gw1[o*MM+m], hn[m], a1);
            y1[o] = fmaxf(a1, 0.f) * sb1[o] + tb1[o];
        }
        #pragma unroll
        for (int p = 0; p < CC2; ++p) {
            float a2 = gb2[p];
            #pragma unroll
            for (int o = 0; o < CC1; ++o) a2 = fmaf(gw2[p*CC1+o], y1[o], a2);
            zb[p*NN + n] = fmaxf(a2, 0.f) * sb2[p] + tb2[p];
        }
    }
}

__global__ __launch_bounds__(256)
void k_fc1(const float* __restrict__ z, const float* __restrict__ W1,
           float* __restrict__ out1_raw)
{
    __shared__ float zs[64*36];
    __shared__ float ws_[32*68];
    const int bt = blockIdx.x, jt = blockIdx.y, ks = blockIdx.z;
    const int t = threadIdx.x;
    const int tb = t >> 4, tj = t & 15;
    const int k0 = ks * GK_CHUNK;
    const int kend = min(k0 + GK_CHUNK, KK1);
    float acc[4][4] = {};
    const int zrow = t >> 2, zcol = (t & 3) * 8;
    const int wrow = t >> 3, wcol = (t & 7) * 8;

    for (int kc = k0; kc < kend; kc += 32) {
        const float* zsrc = z + (size_t)(bt*64 + zrow)*KK1 + kc + zcol;
        #pragma unroll
        for (int q = 0; q < 2; ++q) {
            int k = kc + zcol + q*4;
            float4 v;
            if (k + 3 < kend) v = *reinterpret_cast<const float4*>(zsrc + q*4);
            else {
                v.x = (k+0 < kend) ? zsrc[q*4+0] : 0.f;
                v.y = (k+1 < kend) ? zsrc[q*4+1] : 0.f;
                v.z = (k+2 < kend) ? zsrc[q*4+2] : 0.f;
                v.w = (k+3 < kend) ? zsrc[q*4+3] : 0.f;
            }
            *reinterpret_cast<float4*>(&zs[zrow*36 + zcol + q*4]) = v;
        }
        {
            int k = kc + wrow;
            const float* wsrc = W1 + (size_t)k*HH1 + jt*64 + wcol;
            #pragma unroll
            for (int q = 0; q < 2; ++q) {
                float4 v;
                if (k < kend) v = *reinterpret_cast<const float4*>(wsrc + q*4);
                else v = float4{0.f,0.f,0.f,0.f};
                *reinterpret_cast<float4*>(&ws_[wrow*68 + wcol + q*4]) = v;
            }
        }
        __syncthreads();
        #pragma unroll
        for (int kk = 0; kk < 32; ++kk) {
            float4 w4 = *reinterpret_cast<const float4*>(&ws_[kk*68 + tj*4]);
            float zv[4], wv[4] = {w4.x, w4.y, w4.z, w4.w};
            #pragma unroll
            for (int ib = 0; ib < 4; ++ib) zv[ib] = zs[(tb*4+ib)*36 + kk];
            #pragma unroll
            for (int ib = 0; ib < 4; ++ib)
                #pragma unroll
                for (int ij = 0; ij < 4; ++ij)
                    acc[ib][ij] = fmaf(zv[ib], wv[ij], acc[ib][ij]);
        }
        __syncthreads();
    }
    #pragma unroll
    for (int ib = 0; ib < 4; ++ib) {
        int row = bt*64 + tb*4 + ib;
        #pragma unroll
        for (int ij = 0; ij < 4; ++ij)
            unsafeAtomicAdd(&out1_raw[row*HH1 + jt*64 + tj*4 + ij], acc[ib][ij]);
    }
}

__global__ __launch_bounds__(256)
void k_tail(const float* __restrict__ out1_raw,
            const float* __restrict__ fc_b1, const float* __restrict__ fbn1_g,
            const float* __restrict__ fbn1_b,
            const float* __restrict__ W2, const float* __restrict__ fc_b2,
            const float* __restrict__ fbn2_g, const float* __restrict__ fbn2_b,
            const float* __restrict__ fc1_w, const float* __restrict__ fc1_b,
            float* __restrict__ out)
{
    __shared__ float o1s[HH1];
    const int b = blockIdx.x, t = threadIdx.x;
    float raw = out1_raw[b*HH1 + t] + fc_b1[t];
    o1s[t] = fmaxf(raw * (BN_SCALE * fbn1_g[t]) + fbn1_b[t], 0.f);
    __syncthreads();
    if (t < HH2) {
        float acc = fc_b2[t];
        #pragma unroll 4
        for (int j = 0; j < HH1; ++j) acc = fmaf(o1s[j], W2[j*HH2 + t], acc);
        float v2 = fmaxf(acc * (BN_SCALE * fbn2_g[t]) + fbn2_b[t], 0.f);
        float c = v2 * fc1_w[t];
        #pragma unroll
        for (int off = 32; off; off >>= 1) c += __shfl_down(c, off);
        if (t == 0) out[b] = c + fc1_b[0];
    }
}

extern "C" void kernel_launch(void* const* d_in, const int* in_sizes, int n_in,
                              void* d_out, int out_size, void* d_ws, size_t ws_size,
                              hipStream_t stream)
{
    const float* x      = (const float*)d_in[0];
    const int*   ei     = (const int*)  d_in[1];
    const float* ew     = (const float*)d_in[2];
    const float* w_root = (const float*)d_in[3];
    const float* w_rel  = (const float*)d_in[4];
    const float* b_rel  = (const float*)d_in[5];
    const float* ln_g   = (const float*)d_in[6];
    const float* ln_b   = (const float*)d_in[7];
    const float* gc1_w  = (const float*)d_in[8];
    const float* gc1_b  = (const float*)d_in[9];
    const float* bn1_g  = (const float*)d_in[10];
    const float* bn1_b  = (const float*)d_in[11];
    const float* gc2_w  = (const float*)d_in[12];
    const float* gc2_b  = (const float*)d_in[13];
    const float* bn2_g  = (const float*)d_in[14];
    const float* bn2_b  = (const float*)d_in[15];
    const float* fc_w1  = (const float*)d_in[16];
    const float* fc_b1  = (const float*)d_in[17];
    const float* fbn1_g = (const float*)d_in[18];
    const float* fbn1_b = (const float*)d_in[19];
    const float* fc_w2  = (const float*)d_in[20];
    const float* fc_b2  = (const float*)d_in[21];
    const float* fbn2_g = (const float*)d_in[22];
    const float* fbn2_b = (const float*)d_in[23];
    const float* fc1_w  = (const float*)d_in[24];
    const float* fc1_b  = (const float*)d_in[25];
    float* out = (float*)d_out;

    char* ws = (char*)d_ws;
    // layout: pairs | lens | R{cnt+base, later reused as o1p} | zbuf
    const size_t off_pairs = 0;                                   // 139,460,608
    const size_t off_lens  = off_pairs + (size_t)NBK*CAP*8;       // +4096
    const size_t off_R     = off_lens + 4096;
    const size_t sz_cnt    = (size_t)NBLK*NBK*4;                  // 4,194,304
    const size_t off_cnt   = off_R;
    const size_t off_base  = off_R + sz_cnt;
    const size_t sz_R      = 2*sz_cnt;                            // 8,388,608 (>= o1p 8,126,464)
    const size_t off_zbuf  = off_R + sz_R;
    const size_t need      = off_zbuf + (size_t)BB*KK1*4;

    if (ws_size >= need) {
        uint2*        pairs = (uint2*)(ws + off_pairs);
        unsigned int* lens  = (unsigned int*)(ws + off_lens);
        unsigned int* cnt   = (unsigned int*)(ws + off_cnt);
        unsigned int* base  = (unsigned int*)(ws + off_base);
        float*        zbuf  = (float*)(ws + off_zbuf);
        float*        o1p   = (float*)(ws + off_R);   // reused after k_place

        k_cnt<<<NBLK, TPB, 0, stream>>>(ei + EE, cnt);
        k_scan<<<NBK, 256, 0, stream>>>(cnt, base, lens);
        k_place<<<NBLK, TPB, 0, stream>>>(ei, ei + EE, ew, x, base, pairs);
        k_sample_fused<<<BB, 512, 0, stream>>>(x, pairs, lens,
                                         w_root, w_rel, b_rel, ln_g, ln_b,
                                         gc1_w, gc1_b, bn1_g, bn1_b,
                                         gc2_w, gc2_b, bn2_g, bn2_b, zbuf);
        k_fc1_part<<<dim3(4,4,31), 256, 0, stream>>>(zbuf, fc_w1, o1p);
        k_tail_part<<<BB, 256, 0, stream>>>(o1p, fc_b1, fbn1_g, fbn1_b,
                                       fc_w2, fc_b2, fbn2_g, fbn2_b,
                                       fc1_w, fc1_b, out);
    } else {
        // round-1 fallback (proven <= 11.6 MB ws)
        float* agg      = (float*)(ws);
        float* zbuf     = (float*)(ws + 2259968);
        float* out1_raw = (float*)(ws + 2259968 + 9039872);

        hipMemsetAsync(agg,      0, (size_t)BB*NN*sizeof(float),  stream);
        hipMemsetAsync(out1_raw, 0, (size_t)BB*HH1*sizeof(float), stream);

        k_edge<<<EE/4/256, 256, 0, stream>>>(ei, ei + EE, ew, x, agg);
        k_sample<<<BB, 256, 0, stream>>>(x, agg, w_root, w_rel, b_rel, ln_g, ln_b,
                                         gc1_w, gc1_b, bn1_g, bn1_b,
                                         gc2_w, gc2_b, bn2_g, bn2_b, zbuf);
        k_fc1<<<dim3(4,4,31), 256, 0, stream>>>(zbuf, fc_w1, out1_raw);
        k_tail<<<BB, 256, 0, stream>>>(out1_raw, fc_b1, fbn1_g, fbn1_b,
                                       fc_w2, fc_b2, fbn2_g, fbn2_b,
                                       fc1_w, fc1_b, out);
    }
}

// Round 7
// 377.698 us; speedup vs baseline: 1.3125x; 1.0356x over previous
//
#include <hip/hip_runtime.h>
#include <hip/hip_bf16.h>

#define BB   256
#define NN   2207
#define MM   16
#define EE   16777216
#define CC1  12
#define CC2  4
#define HH1  256
#define HH2  64
#define KK1  (CC2*NN)          /* 8828 */
#define LN_EPS 1e-5f
#define BN_SCALE 0.9999950000374997f   /* 1/sqrt(1+1e-5) */
#define NBK  256               /* buckets == samples */
#define MAGIC 1946067ull       /* ceil(2^32/2207), exact for d < 564992 */
#define EPB  4096              /* edges per bin block */
#define TPB  512
#define EPT  (EPB/TPB)         /* 8 edges per thread */
#define NBLK (EE/EPB)          /* 4096 bin blocks */
#define RSPL 4                 /* replay splits per sample */
#define KPR  (NBLK/RSPL)       /* 1024 bin-blocks per replay block */

static __device__ __forceinline__ unsigned bucket_of(int d) {
    return (unsigned)(((unsigned long long)(unsigned)d * MAGIC) >> 32);
}

// ===== PASS 1: self-contained LDS counting sort -> block-local runs + start table =====
__global__ __launch_bounds__(TPB, 8)
void k_place2(const int* __restrict__ src, const int* __restrict__ dst,
              const float* __restrict__ ew, const float* __restrict__ x,
              uint2* __restrict__ recs, unsigned short* __restrict__ stab)
{
    __shared__ __align__(16) uint2 pl[EPB];     // 32 KB sorted (dst_local, val)
    __shared__ unsigned int hist[NBK], start[NBK];
    __shared__ unsigned int wtot[4];

    const int t = threadIdx.x;
    if (t < NBK) hist[t] = 0;
    __syncthreads();

    const int i4base = blockIdx.x * (EPB/4);
    unsigned pk[EPT];   // bucket(8b) | rank(12b) | dst_local(12b)
    float    pv[EPT];
    #pragma unroll
    for (int q = 0; q < EPT/4; ++q) {
        int i4 = i4base + q*TPB + t;
        int4   s4 = reinterpret_cast<const int4*>(src)[i4];
        int4   d4 = reinterpret_cast<const int4*>(dst)[i4];
        float4 w4 = reinterpret_cast<const float4*>(ew)[i4];
        {
            unsigned b_ = bucket_of(d4.x);
            unsigned r_ = atomicAdd(&hist[b_], 1u);
            pk[q*4+0] = (b_ << 24) | (r_ << 12) | (unsigned)(d4.x - (int)(b_*NN));
            pv[q*4+0] = x[s4.x] * w4.x;
        }
        {
            unsigned b_ = bucket_of(d4.y);
            unsigned r_ = atomicAdd(&hist[b_], 1u);
            pk[q*4+1] = (b_ << 24) | (r_ << 12) | (unsigned)(d4.y - (int)(b_*NN));
            pv[q*4+1] = x[s4.y] * w4.y;
        }
        {
            unsigned b_ = bucket_of(d4.z);
            unsigned r_ = atomicAdd(&hist[b_], 1u);
            pk[q*4+2] = (b_ << 24) | (r_ << 12) | (unsigned)(d4.z - (int)(b_*NN));
            pv[q*4+2] = x[s4.z] * w4.z;
        }
        {
            unsigned b_ = bucket_of(d4.w);
            unsigned r_ = atomicAdd(&hist[b_], 1u);
            pk[q*4+3] = (b_ << 24) | (r_ << 12) | (unsigned)(d4.w - (int)(b_*NN));
            pv[q*4+3] = x[s4.w] * w4.w;
        }
    }
    __syncthreads();

    // exclusive prefix scan of hist[256] (4 waves of 64)
    if (t < NBK) {
        unsigned h = hist[t], v = h;
        #pragma unroll
        for (int off = 1; off < 64; off <<= 1) {
            unsigned u = __shfl_up(v, off);
            if ((t & 63) >= off) v += u;
        }
        start[t] = v - h;
        if ((t & 63) == 63) wtot[t >> 6] = v;
    }
    __syncthreads();
    if (t < NBK) {
        const int w = t >> 6;
        unsigned wo = 0;
        if (w > 0) wo += wtot[0];
        if (w > 1) wo += wtot[1];
        if (w > 2) wo += wtot[2];
        start[t] += wo;
        stab[blockIdx.x * NBK + t] = (unsigned short)(start[t]);
    }
    __syncthreads();

    // scatter into sorted LDS positions
    #pragma unroll
    for (int e = 0; e < EPT; ++e) {
        unsigned b_ = pk[e] >> 24;
        unsigned r_ = (pk[e] >> 12) & 0xFFFu;
        pl[start[b_] + r_] = make_uint2(pk[e] & 0xFFFu, __float_as_uint(pv[e]));
    }
    __syncthreads();

    // linear, perfectly-coalesced flush of the whole sorted block
    uint4* dst4 = reinterpret_cast<uint4*>(recs + (size_t)blockIdx.x * EPB);
    const uint4* src4 = reinterpret_cast<const uint4*>(pl);
    #pragma unroll
    for (int q = 0; q < EPB/2/TPB; ++q)
        dst4[q*TPB + t] = src4[q*TPB + t];
}

// ===== PASS 2a: parallel replay -> partial agg (4 blocks per sample) =====
__global__ __launch_bounds__(TPB, 8)
void k_replay(const uint2* __restrict__ recs, const unsigned short* __restrict__ stab,
              float* __restrict__ paggr)
{
    __shared__ float acc[NN];
    const int t = threadIdx.x;
    const int j = blockIdx.x & (NBK - 1);       // sample
    const int r = blockIdx.x >> 8;              // split index 0..3
    for (int n = t; n < NN; n += TPB) acc[n] = 0.f;
    __syncthreads();

    const int lane = t & 63, w = t >> 6;        // 8 waves
    const int kbase = r * KPR + w * (KPR/8);    // 128 bin-blocks per wave
    #pragma unroll
    for (int h = 0; h < 2; ++h) {
        const int kb = kbase + h*64;
        unsigned s0v = stab[(size_t)(kb + lane) * NBK + j];
        unsigned s1v = (j < NBK-1) ? (unsigned)stab[(size_t)(kb + lane) * NBK + j + 1]
                                   : (unsigned)EPB;
        for (int kk = 0; kk < 64; ++kk) {
            unsigned s0 = __shfl(s0v, kk);
            unsigned s1 = __shfl(s1v, kk);
            const uint2* rp = recs + (size_t)(kb + kk) * EPB;
            for (unsigned b0 = s0; b0 < s1; b0 += 64u) {
                if (b0 + lane < s1) {
                    uint2 rec = rp[b0 + lane];
                    atomicAdd(&acc[rec.x], __uint_as_float(rec.y));
                }
            }
        }
    }
    __syncthreads();
    float* pa = paggr + ((size_t)r * NBK + j) * NN;
    for (int n = t; n < NN; n += TPB) pa[n] = acc[n];
}

// ===== PASS 2b: sum partials + relu/LN/conv1/bn/conv2/bn -> z =====
__global__ __launch_bounds__(512)
void k_ln_conv(const float* __restrict__ x, const float* __restrict__ paggr,
              const float* __restrict__ w_root, const float* __restrict__ w_rel,
              const float* __restrict__ b_rel,
              const float* __restrict__ ln_g, const float* __restrict__ ln_b,
              const float* __restrict__ gc1_w, const float* __restrict__ gc1_b,
              const float* __restrict__ bn1_g, const float* __restrict__ bn1_b,
              const float* __restrict__ gc2_w, const float* __restrict__ gc2_b,
              const float* __restrict__ bn2_g, const float* __restrict__ bn2_b,
              float* __restrict__ z)
{
    __shared__ float xs[NN], acc[NN];
    __shared__ float gw1[CC1*MM], gb1[CC1], sb1[CC1], tb1[CC1];
    __shared__ float gw2[CC2*CC1], gb2[CC2], sb2[CC2], tb2[CC2];
    __shared__ float redS[8], redQ[8];
    __shared__ float s_mu, s_rs;

    const int b = blockIdx.x, t = threadIdx.x;
    const float* xb = x + b*NN;
    for (int n = t; n < NN; n += 512) {
        xs[n] = xb[n];
        float a = 0.f;
        #pragma unroll
        for (int r = 0; r < RSPL; ++r)
            a += paggr[((size_t)r * NBK + b) * NN + n];
        acc[n] = a;
    }
    if (t < CC1*MM) gw1[t] = gc1_w[t];
    if (t >= 192 && t < 192+CC1) { int o = t-192; gb1[o]=gc1_b[o]; sb1[o]=BN_SCALE*bn1_g[o]; tb1[o]=bn1_b[o]; }
    if (t >= 208 && t < 208+CC2*CC1) gw2[t-208] = gc2_w[t-208];
    if (t >= 240 && t < 240+CC2) { int p=t-240; gb2[p]=gc2_b[p]; sb2[p]=BN_SCALE*bn2_g[p]; tb2[p]=bn2_b[p]; }

    float wr[MM], br[MM], wo[MM];
    #pragma unroll
    for (int m = 0; m < MM; ++m) { wr[m]=w_rel[m]; br[m]=b_rel[m]; wo[m]=w_root[m]; }
    __syncthreads();

    // LN statistics over (N, M)
    float S = 0.f, Q = 0.f;
    for (int n = t; n < NN; n += 512) {
        float a = acc[n], xv = xs[n];
        #pragma unroll
        for (int m = 0; m < MM; ++m) {
            float h = fmaxf(fmaf(a, wr[m], fmaf(xv, wo[m], br[m])), 0.f);
            S += h; Q += h*h;
        }
    }
    #pragma unroll
    for (int off = 32; off; off >>= 1) { S += __shfl_down(S, off); Q += __shfl_down(Q, off); }
    if ((t & 63) == 0) { redS[t>>6] = S; redQ[t>>6] = Q; }
    __syncthreads();
    if (t == 0) {
        float SS = 0.f, QQ = 0.f;
        #pragma unroll
        for (int i = 0; i < 8; ++i) { SS += redS[i]; QQ += redQ[i]; }
        const float inv = 1.f / (float)(NN*MM);
        float mu = SS * inv;
        float var = QQ * inv - mu*mu;
        s_mu = mu; s_rs = rsqrtf(var + LN_EPS);
    }
    __syncthreads();
    const float mu = s_mu, rs = s_rs;

    float* zb = z + (size_t)b * KK1;
    for (int n = t; n < NN; n += 512) {
        float a = acc[n], xv = xs[n];
        float hn[MM];
        const float4* g4  = reinterpret_cast<const float4*>(ln_g + n*MM);
        const float4* be4 = reinterpret_cast<const float4*>(ln_b + n*MM);
        #pragma unroll
        for (int q = 0; q < 4; ++q) {
            float4 g = g4[q], be = be4[q];
            float gg[4]  = {g.x, g.y, g.z, g.w};
            float bb_[4] = {be.x, be.y, be.z, be.w};
            #pragma unroll
            for (int j = 0; j < 4; ++j) {
                int m = q*4 + j;
                float h = fmaxf(fmaf(a, wr[m], fmaf(xv, wo[m], br[m])), 0.f);
                hn[m] = (h - mu) * rs * gg[j] + bb_[j];
            }
        }
        float y1[CC1];
        #pragma unroll
        for (int o = 0; o < CC1; ++o) {
            float a1 = gb1[o];
            #pragma unroll
            for (int m = 0; m < MM; ++m) a1 = fmaf(gw1[o*MM+m], hn[m], a1);
            y1[o] = fmaxf(a1, 0.f) * sb1[o] + tb1[o];
        }
        #pragma unroll
        for (int p = 0; p < CC2; ++p) {
            float a2 = gb2[p];
            #pragma unroll
            for (int o = 0; o < CC1; ++o) a2 = fmaf(gw2[p*CC1+o], y1[o], a2);
            zb[p*NN + n] = fmaxf(a2, 0.f) * sb2[p] + tb2[p];
        }
    }
}

// ------------- FC1 GEMM: split-K partials (no atomics) -------------
#define GK_CHUNK 288   /* grid.z = 31; 31*288 = 8928 >= 8828 */
__global__ __launch_bounds__(256)
void k_fc1_part(const float* __restrict__ z, const float* __restrict__ W1,
                float* __restrict__ out1_part)
{
    __shared__ float zs[64*36];
    __shared__ float ws_[32*68];
    const int bt = blockIdx.x, jt = blockIdx.y, ks = blockIdx.z;
    const int t = threadIdx.x;
    const int tb = t >> 4, tj = t & 15;
    const int k0 = ks * GK_CHUNK;
    const int kend = min(k0 + GK_CHUNK, KK1);
    float acc[4][4] = {};
    const int zrow = t >> 2, zcol = (t & 3) * 8;
    const int wrow = t >> 3, wcol = (t & 7) * 8;

    for (int kc = k0; kc < kend; kc += 32) {
        const float* zsrc = z + (size_t)(bt*64 + zrow)*KK1 + kc + zcol;
        #pragma unroll
        for (int q = 0; q < 2; ++q) {
            int k = kc + zcol + q*4;
            float4 v;
            if (k + 3 < kend) v = *reinterpret_cast<const float4*>(zsrc + q*4);
            else {
                v.x = (k+0 < kend) ? zsrc[q*4+0] : 0.f;
                v.y = (k+1 < kend) ? zsrc[q*4+1] : 0.f;
                v.z = (k+2 < kend) ? zsrc[q*4+2] : 0.f;
                v.w = (k+3 < kend) ? zsrc[q*4+3] : 0.f;
            }
            *reinterpret_cast<float4*>(&zs[zrow*36 + zcol + q*4]) = v;
        }
        {
            int k = kc + wrow;
            const float* wsrc = W1 + (size_t)k*HH1 + jt*64 + wcol;
            #pragma unroll
            for (int q = 0; q < 2; ++q) {
                float4 v;
                if (k < kend) v = *reinterpret_cast<const float4*>(wsrc + q*4);
                else v = float4{0.f,0.f,0.f,0.f};
                *reinterpret_cast<float4*>(&ws_[wrow*68 + wcol + q*4]) = v;
            }
        }
        __syncthreads();
        #pragma unroll
        for (int kk = 0; kk < 32; ++kk) {
            float4 w4 = *reinterpret_cast<const float4*>(&ws_[kk*68 + tj*4]);
            float zv[4], wv[4] = {w4.x, w4.y, w4.z, w4.w};
            #pragma unroll
            for (int ib = 0; ib < 4; ++ib) zv[ib] = zs[(tb*4+ib)*36 + kk];
            #pragma unroll
            for (int ib = 0; ib < 4; ++ib)
                #pragma unroll
                for (int ij = 0; ij < 4; ++ij)
                    acc[ib][ij] = fmaf(zv[ib], wv[ij], acc[ib][ij]);
        }
        __syncthreads();
    }
    #pragma unroll
    for (int ib = 0; ib < 4; ++ib) {
        int row = bt*64 + tb*4 + ib;
        float4 v = make_float4(acc[ib][0], acc[ib][1], acc[ib][2], acc[ib][3]);
        *reinterpret_cast<float4*>(
            &out1_part[((size_t)ks*256 + row)*HH1 + jt*64 + tj*4]) = v;
    }
}

// ------------- tail: sum partials -> bn-relu -> FC2 -> bn-relu -> dot -------------
__global__ __launch_bounds__(256)
void k_tail_part(const float* __restrict__ out1_part,
            const float* __restrict__ fc_b1, const float* __restrict__ fbn1_g,
            const float* __restrict__ fbn1_b,
            const float* __restrict__ W2, const float* __restrict__ fc_b2,
            const float* __restrict__ fbn2_g, const float* __restrict__ fbn2_b,
            const float* __restrict__ fc1_w, const float* __restrict__ fc1_b,
            float* __restrict__ out)
{
    __shared__ float o1s[HH1];
    const int b = blockIdx.x, t = threadIdx.x;
    float raw = fc_b1[t];
    #pragma unroll 4
    for (int ks = 0; ks < 31; ++ks)
        raw += out1_part[((size_t)ks*256 + b)*HH1 + t];
    o1s[t] = fmaxf(raw * (BN_SCALE * fbn1_g[t]) + fbn1_b[t], 0.f);
    __syncthreads();
    if (t < HH2) {
        float acc = fc_b2[t];
        #pragma unroll 4
        for (int j = 0; j < HH1; ++j) acc = fmaf(o1s[j], W2[j*HH2 + t], acc);
        float v2 = fmaxf(acc * (BN_SCALE * fbn2_g[t]) + fbn2_b[t], 0.f);
        float c = v2 * fc1_w[t];
        #pragma unroll
        for (int off = 32; off; off >>= 1) c += __shfl_down(c, off);
        if (t == 0) out[b] = c + fc1_b[0];
    }
}

// =================== fallback path (round-1, proven; used if ws too small) ===================
__global__ __launch_bounds__(256)
void k_edge(const int* __restrict__ src, const int* __restrict__ dst,
            const float* __restrict__ ew, const float* __restrict__ x,
            float* __restrict__ agg)
{
    int i = blockIdx.x * 256 + threadIdx.x;
    const int4   s4 = reinterpret_cast<const int4*>(src)[i];
    const int4   d4 = reinterpret_cast<const int4*>(dst)[i];
    const float4 w4 = reinterpret_cast<const float4*>(ew)[i];
    unsafeAtomicAdd(&agg[d4.x], x[s4.x] * w4.x);
    unsafeAtomicAdd(&agg[d4.y], x[s4.y] * w4.y);
    unsafeAtomicAdd(&agg[d4.z], x[s4.z] * w4.z);
    unsafeAtomicAdd(&agg[d4.w], x[s4.w] * w4.w);
}

__global__ __launch_bounds__(256)
void k_sample(const float* __restrict__ x, const float* __restrict__ agg,
              const float* __restrict__ w_root, const float* __restrict__ w_rel,
              const float* __restrict__ b_rel,
              const float* __restrict__ ln_g, const float* __restrict__ ln_b,
              const float* __restrict__ gc1_w, const float* __restrict__ gc1_b,
              const float* __restrict__ bn1_g, const float* __restrict__ bn1_b,
              const float* __restrict__ gc2_w, const float* __restrict__ gc2_b,
              const float* __restrict__ bn2_g, const float* __restrict__ bn2_b,
              float* __restrict__ z)
{
    __shared__ float xs[NN], as[NN];
    __shared__ float gw1[CC1*MM], gb1[CC1], sb1[CC1], tb1[CC1];
    __shared__ float gw2[CC2*CC1], gb2[CC2], sb2[CC2], tb2[CC2];
    __shared__ float redS[4], redQ[4];
    __shared__ float s_mu, s_rs;

    const int b = blockIdx.x, t = threadIdx.x;
    const float* xb = x + b*NN;
    const float* ab = agg + b*NN;
    for (int n = t; n < NN; n += 256) { xs[n] = xb[n]; as[n] = ab[n]; }
    if (t < CC1*MM) gw1[t] = gc1_w[t];
    if (t >= 192 && t < 192+CC1) { int o = t-192; gb1[o]=gc1_b[o]; sb1[o]=BN_SCALE*bn1_g[o]; tb1[o]=bn1_b[o]; }
    if (t >= 208 && t < 208+CC2*CC1) gw2[t-208] = gc2_w[t-208];
    if (t >= 240 && t < 240+CC2) { int p=t-240; gb2[p]=gc2_b[p]; sb2[p]=BN_SCALE*bn2_g[p]; tb2[p]=bn2_b[p]; }

    float wr[MM], br[MM], wo[MM];
    #pragma unroll
    for (int m = 0; m < MM; ++m) { wr[m]=w_rel[m]; br[m]=b_rel[m]; wo[m]=w_root[m]; }
    __syncthreads();

    float S = 0.f, Q = 0.f;
    for (int n = t; n < NN; n += 256) {
        float a = as[n], xv = xs[n];
        #pragma unroll
        for (int m = 0; m < MM; ++m) {
            float h = fmaxf(fmaf(a, wr[m], fmaf(xv, wo[m], br[m])), 0.f);
            S += h; Q += h*h;
        }
    }
    #pragma unroll
    for (int off = 32; off; off >>= 1) { S += __shfl_down(S, off); Q += __shfl_down(Q, off); }
    if ((t & 63) == 0) { redS[t>>6] = S; redQ[t>>6] = Q; }
    __syncthreads();
    if (t == 0) {
        float SS = redS[0]+redS[1]+redS[2]+redS[3];
        float QQ = redQ[0]+redQ[1]+redQ[2]+redQ[3];
        const float inv = 1.f / (float)(NN*MM);
        float mu = SS * inv;
        float var = QQ * inv - mu*mu;
        s_mu = mu; s_rs = rsqrtf(var + LN_EPS);
    }
    __syncthreads();
    const float mu = s_mu, rs = s_rs;

    float* zb = z + (size_t)b * KK1;
    for (int n = t; n < NN; n += 256) {
        float a = as[n], xv = xs[n];
        float hn[MM];
        const float4* g4  = reinterpret_cast<const float4*>(ln_g + n*MM);
        const float4* be4 = reinterpret_cast<const float4*>(ln_b + n*MM);
        #pragma unroll
        for (int q = 0; q < 4; ++q) {
            float4 g = g4[q], be = be4[q];
            float gg[4]  = {g.x, g.y, g.z, g.w};
            float bb_[4] = {be.x, be.y, be.z, be.w};
            #pragma unroll
            for (int j = 0; j < 4; ++j) {
                int m = q*4 + j;
                float h = fmaxf(fmaf(a, wr[m], fmaf(xv, wo[m], br[m])), 0.f);
                hn[m] = (h - mu) * rs * gg[j] + bb_[j];
            }
        }
        float y1[CC1];
        #pragma unroll
        for (int o = 0; o < CC1; ++o) {
            float a1 = gb1[o];
            #pragma unroll
            for (int m = 0; m < MM; ++m) a1 = fmaf(gw1[o*MM+m], hn[m], a1);
            y1[o] = fmaxf(a1, 0.f) * sb1[o] + tb1[o];
        }
        #pragma unroll
        for (int p = 0; p < CC2; ++p) {
            float a2 = gb2[p];
            #pragma unroll
            for (int o = 0; o < CC1; ++o) a2 = fmaf(gw2[p*CC1+o], y1[o], a2);
            zb[p*NN + n] = fmaxf(a2, 0.f) * sb2[p] + tb2[p];
        }
    }
}

__global__ __launch_bounds__(256)
void k_fc1(const float* __restrict__ z, const float* __restrict__ W1,
           float* __restrict__ out1_raw)
{
    __shared__ float zs[64*36];
    __shared__ float ws_[32*68];
    const int bt = blockIdx.x, jt = blockIdx.y, ks = blockIdx.z;
    const int t = threadIdx.x;
    const int tb = t >> 4, tj = t & 15;
    const int k0 = ks * GK_CHUNK;
    const int kend = min(k0 + GK_CHUNK, KK1);
    float acc[4][4] = {};
    const int zrow = t >> 2, zcol = (t & 3) * 8;
    const int wrow = t >> 3, wcol = (t & 7) * 8;

    for (int kc = k0; kc < kend; kc += 32) {
        const float* zsrc = z + (size_t)(bt*64 + zrow)*KK1 + kc + zcol;
        #pragma unroll
        for (int q = 0; q < 2; ++q) {
            int k = kc + zcol + q*4;
            float4 v;
            if (k + 3 < kend) v = *reinterpret_cast<const float4*>(zsrc + q*4);
            else {
                v.x = (k+0 < kend) ? zsrc[q*4+0] : 0.f;
                v.y = (k+1 < kend) ? zsrc[q*4+1] : 0.f;
                v.z = (k+2 < kend) ? zsrc[q*4+2] : 0.f;
                v.w = (k+3 < kend) ? zsrc[q*4+3] : 0.f;
            }
            *reinterpret_cast<float4*>(&zs[zrow*36 + zcol + q*4]) = v;
        }
        {
            int k = kc + wrow;
            const float* wsrc = W1 + (size_t)k*HH1 + jt*64 + wcol;
            #pragma unroll
            for (int q = 0; q < 2; ++q) {
                float4 v;
                if (k < kend) v = *reinterpret_cast<const float4*>(wsrc + q*4);
                else v = float4{0.f,0.f,0.f,0.f};
                *reinterpret_cast<float4*>(&ws_[wrow*68 + wcol + q*4]) = v;
            }
        }
        __syncthreads();
        #pragma unroll
        for (int kk = 0; kk < 32; ++kk) {
            float4 w4 = *reinterpret_cast<const float4*>(&ws_[kk*68 + tj*4]);
            float zv[4], wv[4] = {w4.x, w4.y, w4.z, w4.w};
            #pragma unroll
            for (int ib = 0; ib < 4; ++ib) zv[ib] = zs[(tb*4+ib)*36 + kk];
            #pragma unroll
            for (int ib = 0; ib < 4; ++ib)
                #pragma unroll
                for (int ij = 0; ij < 4; ++ij)
                    acc[ib][ij] = fmaf(zv[ib], wv[ij], acc[ib][ij]);
        }
        __syncthreads();
    }
    #pragma unroll
    for (int ib = 0; ib < 4; ++ib) {
        int row = bt*64 + tb*4 + ib;
        #pragma unroll
        for (int ij = 0; ij < 4; ++ij)
            unsafeAtomicAdd(&out1_raw[row*HH1 + jt*64 + tj*4 + ij], acc[ib][ij]);
    }
}

__global__ __launch_bounds__(256)
void k_tail(const float* __restrict__ out1_raw,
            const float* __restrict__ fc_b1, const float* __restrict__ fbn1_g,
            const float* __restrict__ fbn1_b,
            const float* __restrict__ W2, const float* __restrict__ fc_b2,
            const float* __restrict__ fbn2_g, const float* __restrict__ fbn2_b,
            const float* __restrict__ fc1_w, const float* __restrict__ fc1_b,
            float* __restrict__ out)
{
    __shared__ float o1s[HH1];
    const int b = blockIdx.x, t = threadIdx.x;
    float raw = out1_raw[b*HH1 + t] + fc_b1[t];
    o1s[t] = fmaxf(raw * (BN_SCALE * fbn1_g[t]) + fbn1_b[t], 0.f);
    __syncthreads();
    if (t < HH2) {
        float acc = fc_b2[t];
        #pragma unroll 4
        for (int j = 0; j < HH1; ++j) acc = fmaf(o1s[j], W2[j*HH2 + t], acc);
        float v2 = fmaxf(acc * (BN_SCALE * fbn2_g[t]) + fbn2_b[t], 0.f);
        float c = v2 * fc1_w[t];
        #pragma unroll
        for (int off = 32; off; off >>= 1) c += __shfl_down(c, off);
        if (t == 0) out[b] = c + fc1_b[0];
    }
}

extern "C" void kernel_launch(void* const* d_in, const int* in_sizes, int n_in,
                              void* d_out, int out_size, void* d_ws, size_t ws_size,
                              hipStream_t stream)
{
    const float* x      = (const float*)d_in[0];
    const int*   ei     = (const int*)  d_in[1];
    const float* ew     = (const float*)d_in[2];
    const float* w_root = (const float*)d_in[3];
    const float* w_rel  = (const float*)d_in[4];
    const float* b_rel  = (const float*)d_in[5];
    const float* ln_g   = (const float*)d_in[6];
    const float* ln_b   = (const float*)d_in[7];
    const float* gc1_w  = (const float*)d_in[8];
    const float* gc1_b  = (const float*)d_in[9];
    const float* bn1_g  = (const float*)d_in[10];
    const float* bn1_b  = (const float*)d_in[11];
    const float* gc2_w  = (const float*)d_in[12];
    const float* gc2_b  = (const float*)d_in[13];
    const float* bn2_g  = (const float*)d_in[14];
    const float* bn2_b  = (const float*)d_in[15];
    const float* fc_w1  = (const float*)d_in[16];
    const float* fc_b1  = (const float*)d_in[17];
    const float* fbn1_g = (const float*)d_in[18];
    const float* fbn1_b = (const float*)d_in[19];
    const float* fc_w2  = (const float*)d_in[20];
    const float* fc_b2  = (const float*)d_in[21];
    const float* fbn2_g = (const float*)d_in[22];
    const float* fbn2_b = (const float*)d_in[23];
    const float* fc1_w  = (const float*)d_in[24];
    const float* fc1_b  = (const float*)d_in[25];
    float* out = (float*)d_out;

    char* ws = (char*)d_ws;
    // layout: recs | stab | paggr (reused as o1p) | zbuf    = 154.4 MB total
    const size_t off_recs  = 0;                                   // 4096*4096*8 = 134,217,728
    const size_t off_stab  = off_recs + (size_t)NBLK*EPB*8;       // +2,097,152
    const size_t off_paggr = off_stab + (size_t)NBLK*NBK*2;       // +9,039,872 (>= o1p 8,126,464)
    const size_t off_zbuf  = off_paggr + (size_t)RSPL*NBK*NN*4;
    const size_t need      = off_zbuf + (size_t)BB*KK1*4;

    if (ws_size >= need) {
        uint2*          recs  = (uint2*)(ws + off_recs);
        unsigned short* stab  = (unsigned short*)(ws + off_stab);
        float*          paggr = (float*)(ws + off_paggr);
        float*          zbuf  = (float*)(ws + off_zbuf);
        float*          o1p   = (float*)(ws + off_paggr);  // reused after k_ln_conv

        k_place2<<<NBLK, TPB, 0, stream>>>(ei, ei + EE, ew, x, recs, stab);
        k_replay<<<NBK*RSPL, TPB, 0, stream>>>(recs, stab, paggr);
        k_ln_conv<<<BB, 512, 0, stream>>>(x, paggr,
                                         w_root, w_rel, b_rel, ln_g, ln_b,
                                         gc1_w, gc1_b, bn1_g, bn1_b,
                                         gc2_w, gc2_b, bn2_g, bn2_b, zbuf);
        k_fc1_part<<<dim3(4,4,31), 256, 0, stream>>>(zbuf, fc_w1, o1p);
        k_tail_part<<<BB, 256, 0, stream>>>(o1p, fc_b1, fbn1_g, fbn1_b,
                                       fc_w2, fc_b2, fbn2_g, fbn2_b,
                                       fc1_w, fc1_b, out);
    } else {
        // round-1 fallback (proven <= 11.6 MB ws)
        float* agg      = (float*)(ws);
        float* zbuf     = (float*)(ws + 2259968);
        float* out1_raw = (float*)(ws + 2259968 + 9039872);

        hipMemsetAsync(agg,      0, (size_t)BB*NN*sizeof(float),  stream);
        hipMemsetAsync(out1_raw, 0, (size_t)BB*HH1*sizeof(float), stream);

        k_edge<<<EE/4/256, 256, 0, stream>>>(ei, ei + EE, ew, x, agg);
        k_sample<<<BB, 256, 0, stream>>>(x, agg, w_root, w_rel, b_rel, ln_g, ln_b,
                                         gc1_w, gc1_b, bn1_g, bn1_b,
                                         gc2_w, gc2_b, bn2_g, bn2_b, zbuf);
        k_fc1<<<dim3(4,4,31), 256, 0, stream>>>(zbuf, fc_w1, out1_raw);
        k_tail<<<BB, 256, 0, stream>>>(out1_raw, fc_b1, fbn1_g, fbn1_b,
                                       fc_w2, fc_b2, fbn2_g, fbn2_b,
                                       fc1_w, fc1_b, out);
    }
}

// Round 8
// 346.254 us; speedup vs baseline: 1.4317x; 1.0908x over previous
//
#include <hip/hip_runtime.h>
#include <hip/hip_bf16.h>

#define BB   256
#define NN   2207
#define MM   16
#define EE   16777216
#define CC1  12
#define CC2  4
#define HH1  256
#define HH2  64
#define KK1  (CC2*NN)          /* 8828 */
#define LN_EPS 1e-5f
#define BN_SCALE 0.9999950000374997f   /* 1/sqrt(1+1e-5) */
#define NBK  256               /* buckets == samples */
#define MAGIC 1946067ull       /* ceil(2^32/2207), exact for d < 564992 */
#define EPB  4096              /* edges per bin block */
#define TPB  512
#define EPT  (EPB/TPB)         /* 8 edges per thread */
#define NBLK (EE/EPB)          /* 4096 bin blocks */

static __device__ __forceinline__ unsigned bucket_of(int d) {
    return (unsigned)(((unsigned long long)(unsigned)d * MAGIC) >> 32);
}

// ===== PASS 1: self-contained LDS counting sort -> block-local runs + start table =====
__global__ __launch_bounds__(TPB, 8)
void k_place2(const int* __restrict__ src, const int* __restrict__ dst,
              const float* __restrict__ ew, const float* __restrict__ x,
              uint2* __restrict__ recs, unsigned short* __restrict__ stab)
{
    __shared__ __align__(16) uint2 pl[EPB];     // 32 KB sorted (dst_local, val)
    __shared__ unsigned int hist[NBK], start[NBK];
    __shared__ unsigned int wtot[4];

    const int t = threadIdx.x;
    if (t < NBK) hist[t] = 0;
    __syncthreads();

    const int i4base = blockIdx.x * (EPB/4);
    unsigned pk[EPT];   // bucket(8b) | rank(12b) | dst_local(12b)
    float    pv[EPT];
    #pragma unroll
    for (int q = 0; q < EPT/4; ++q) {
        int i4 = i4base + q*TPB + t;
        int4   s4 = reinterpret_cast<const int4*>(src)[i4];
        int4   d4 = reinterpret_cast<const int4*>(dst)[i4];
        float4 w4 = reinterpret_cast<const float4*>(ew)[i4];
        {
            unsigned b_ = bucket_of(d4.x);
            unsigned r_ = atomicAdd(&hist[b_], 1u);
            pk[q*4+0] = (b_ << 24) | (r_ << 12) | (unsigned)(d4.x - (int)(b_*NN));
            pv[q*4+0] = x[s4.x] * w4.x;
        }
        {
            unsigned b_ = bucket_of(d4.y);
            unsigned r_ = atomicAdd(&hist[b_], 1u);
            pk[q*4+1] = (b_ << 24) | (r_ << 12) | (unsigned)(d4.y - (int)(b_*NN));
            pv[q*4+1] = x[s4.y] * w4.y;
        }
        {
            unsigned b_ = bucket_of(d4.z);
            unsigned r_ = atomicAdd(&hist[b_], 1u);
            pk[q*4+2] = (b_ << 24) | (r_ << 12) | (unsigned)(d4.z - (int)(b_*NN));
            pv[q*4+2] = x[s4.z] * w4.z;
        }
        {
            unsigned b_ = bucket_of(d4.w);
            unsigned r_ = atomicAdd(&hist[b_], 1u);
            pk[q*4+3] = (b_ << 24) | (r_ << 12) | (unsigned)(d4.w - (int)(b_*NN));
            pv[q*4+3] = x[s4.w] * w4.w;
        }
    }
    __syncthreads();

    // exclusive prefix scan of hist[256] (4 waves of 64)
    if (t < NBK) {
        unsigned h = hist[t], v = h;
        #pragma unroll
        for (int off = 1; off < 64; off <<= 1) {
            unsigned u = __shfl_up(v, off);
            if ((t & 63) >= off) v += u;
        }
        start[t] = v - h;
        if ((t & 63) == 63) wtot[t >> 6] = v;
    }
    __syncthreads();
    if (t < NBK) {
        const int w = t >> 6;
        unsigned wo = 0;
        if (w > 0) wo += wtot[0];
        if (w > 1) wo += wtot[1];
        if (w > 2) wo += wtot[2];
        start[t] += wo;
        stab[blockIdx.x * NBK + t] = (unsigned short)(start[t]);
    }
    __syncthreads();

    // scatter into sorted LDS positions
    #pragma unroll
    for (int e = 0; e < EPT; ++e) {
        unsigned b_ = pk[e] >> 24;
        unsigned r_ = (pk[e] >> 12) & 0xFFFu;
        pl[start[b_] + r_] = make_uint2(pk[e] & 0xFFFu, __float_as_uint(pv[e]));
    }
    __syncthreads();

    // linear, perfectly-coalesced flush of the whole sorted block
    uint4* dst4 = reinterpret_cast<uint4*>(recs + (size_t)blockIdx.x * EPB);
    const uint4* src4 = reinterpret_cast<const uint4*>(pl);
    #pragma unroll
    for (int q = 0; q < EPB/2/TPB; ++q)
        dst4[q*TPB + t] = src4[q*TPB + t];
}

// ===== PASS 2a: group-run replay -> partial agg (rspl blocks per sample) =====
// 16-lane groups each process one bin-block's run for sample j (avg run = 16).
#define RTPB 256
__global__ __launch_bounds__(RTPB, 8)
void k_replay2(const uint2* __restrict__ recs, const unsigned short* __restrict__ stab,
               float* __restrict__ paggr, int rspl)
{
    __shared__ float acc[NN];
    const int t = threadIdx.x;
    const int j = blockIdx.x & (NBK - 1);       // sample
    const int r = blockIdx.x >> 8;              // split index 0..rspl-1
    const int kpr = NBLK / rspl;                // bin-blocks per replay block
    for (int n = t; n < NN; n += RTPB) acc[n] = 0.f;
    __syncthreads();

    const int gid = t >> 4, l16 = t & 15;       // 16 groups of 16 lanes
    const int kb0 = r * kpr;
    for (int kb_i = gid; kb_i < kpr; kb_i += RTPB/16) {
        const int kb = kb0 + kb_i;
        unsigned s0 = stab[(size_t)kb * NBK + j];
        unsigned s1 = (j < NBK-1) ? (unsigned)stab[(size_t)kb * NBK + j + 1]
                                  : (unsigned)EPB;
        const uint2* rp = recs + (size_t)kb * EPB;
        for (unsigned u = s0 + (unsigned)l16; u < s1; u += 16u) {
            uint2 rec = rp[u];
            atomicAdd(&acc[rec.x], __uint_as_float(rec.y));
        }
    }
    __syncthreads();
    float* pa = paggr + ((size_t)r * NBK + j) * NN;
    for (int n = t; n < NN; n += RTPB) pa[n] = acc[n];
}

// ===== PASS 2b: sum partials + relu/LN/conv1/bn/conv2/bn -> z =====
__global__ __launch_bounds__(512)
void k_ln_conv(const float* __restrict__ x, const float* __restrict__ paggr,
              const float* __restrict__ w_root, const float* __restrict__ w_rel,
              const float* __restrict__ b_rel,
              const float* __restrict__ ln_g, const float* __restrict__ ln_b,
              const float* __restrict__ gc1_w, const float* __restrict__ gc1_b,
              const float* __restrict__ bn1_g, const float* __restrict__ bn1_b,
              const float* __restrict__ gc2_w, const float* __restrict__ gc2_b,
              const float* __restrict__ bn2_g, const float* __restrict__ bn2_b,
              float* __restrict__ z, int rspl)
{
    __shared__ float xs[NN], acc[NN];
    __shared__ float gw1[CC1*MM], gb1[CC1], sb1[CC1], tb1[CC1];
    __shared__ float gw2[CC2*CC1], gb2[CC2], sb2[CC2], tb2[CC2];
    __shared__ float redS[8], redQ[8];
    __shared__ float s_mu, s_rs;

    const int b = blockIdx.x, t = threadIdx.x;
    const float* xb = x + b*NN;
    for (int n = t; n < NN; n += 512) {
        xs[n] = xb[n];
        float a = 0.f;
        for (int r = 0; r < rspl; ++r)
            a += paggr[((size_t)r * NBK + b) * NN + n];
        acc[n] = a;
    }
    if (t < CC1*MM) gw1[t] = gc1_w[t];
    if (t >= 192 && t < 192+CC1) { int o = t-192; gb1[o]=gc1_b[o]; sb1[o]=BN_SCALE*bn1_g[o]; tb1[o]=bn1_b[o]; }
    if (t >= 208 && t < 208+CC2*CC1) gw2[t-208] = gc2_w[t-208];
    if (t >= 240 && t < 240+CC2) { int p=t-240; gb2[p]=gc2_b[p]; sb2[p]=BN_SCALE*bn2_g[p]; tb2[p]=bn2_b[p]; }

    float wr[MM], br[MM], wo[MM];
    #pragma unroll
    for (int m = 0; m < MM; ++m) { wr[m]=w_rel[m]; br[m]=b_rel[m]; wo[m]=w_root[m]; }
    __syncthreads();

    // LN statistics over (N, M)
    float S = 0.f, Q = 0.f;
    for (int n = t; n < NN; n += 512) {
        float a = acc[n], xv = xs[n];
        #pragma unroll
        for (int m = 0; m < MM; ++m) {
            float h = fmaxf(fmaf(a, wr[m], fmaf(xv, wo[m], br[m])), 0.f);
            S += h; Q += h*h;
        }
    }
    #pragma unroll
    for (int off = 32; off; off >>= 1) { S += __shfl_down(S, off); Q += __shfl_down(Q, off); }
    if ((t & 63) == 0) { redS[t>>6] = S; redQ[t>>6] = Q; }
    __syncthreads();
    if (t == 0) {
        float SS = 0.f, QQ = 0.f;
        #pragma unroll
        for (int i = 0; i < 8; ++i) { SS += redS[i]; QQ += redQ[i]; }
        const float inv = 1.f / (float)(NN*MM);
        float mu = SS * inv;
        float var = QQ * inv - mu*mu;
        s_mu = mu; s_rs = rsqrtf(var + LN_EPS);
    }
    __syncthreads();
    const float mu = s_mu, rs = s_rs;

    float* zb = z + (size_t)b * KK1;
    for (int n = t; n < NN; n += 512) {
        float a = acc[n], xv = xs[n];
        float hn[MM];
        const float4* g4  = reinterpret_cast<const float4*>(ln_g + n*MM);
        const float4* be4 = reinterpret_cast<const float4*>(ln_b + n*MM);
        #pragma unroll
        for (int q = 0; q < 4; ++q) {
            float4 g = g4[q], be = be4[q];
            float gg[4]  = {g.x, g.y, g.z, g.w};
            float bb_[4] = {be.x, be.y, be.z, be.w};
            #pragma unroll
            for (int j = 0; j < 4; ++j) {
                int m = q*4 + j;
                float h = fmaxf(fmaf(a, wr[m], fmaf(xv, wo[m], br[m])), 0.f);
                hn[m] = (h - mu) * rs * gg[j] + bb_[j];
            }
        }
        float y1[CC1];
        #pragma unroll
        for (int o = 0; o < CC1; ++o) {
            float a1 = gb1[o];
            #pragma unroll
            for (int m = 0; m < MM; ++m) a1 = fmaf(gw1[o*MM+m], hn[m], a1);
            y1[o] = fmaxf(a1, 0.f) * sb1[o] + tb1[o];
        }
        #pragma unroll
        for (int p = 0; p < CC2; ++p) {
            float a2 = gb2[p];
            #pragma unroll
            for (int o = 0; o < CC1; ++o) a2 = fmaf(gw2[p*CC1+o], y1[o], a2);
            zb[p*NN + n] = fmaxf(a2, 0.f) * sb2[p] + tb2[p];
        }
    }
}

// ------------- FC1 GEMM: split-K partials (no atomics) -------------
#define GK_CHUNK 288   /* grid.z = 31; 31*288 = 8928 >= 8828 */
__global__ __launch_bounds__(256)
void k_fc1_part(const float* __restrict__ z, const float* __restrict__ W1,
                float* __restrict__ out1_part)
{
    __shared__ float zs[64*36];
    __shared__ float ws_[32*68];
    const int bt = blockIdx.x, jt = blockIdx.y, ks = blockIdx.z;
    const int t = threadIdx.x;
    const int tb = t >> 4, tj = t & 15;
    const int k0 = ks * GK_CHUNK;
    const int kend = min(k0 + GK_CHUNK, KK1);
    float acc[4][4] = {};
    const int zrow = t >> 2, zcol = (t & 3) * 8;
    const int wrow = t >> 3, wcol = (t & 7) * 8;

    for (int kc = k0; kc < kend; kc += 32) {
        const float* zsrc = z + (size_t)(bt*64 + zrow)*KK1 + kc + zcol;
        #pragma unroll
        for (int q = 0; q < 2; ++q) {
            int k = kc + zcol + q*4;
            float4 v;
            if (k + 3 < kend) v = *reinterpret_cast<const float4*>(zsrc + q*4);
            else {
                v.x = (k+0 < kend) ? zsrc[q*4+0] : 0.f;
                v.y = (k+1 < kend) ? zsrc[q*4+1] : 0.f;
                v.z = (k+2 < kend) ? zsrc[q*4+2] : 0.f;
                v.w = (k+3 < kend) ? zsrc[q*4+3] : 0.f;
            }
            *reinterpret_cast<float4*>(&zs[zrow*36 + zcol + q*4]) = v;
        }
        {
            int k = kc + wrow;
            const float* wsrc = W1 + (size_t)k*HH1 + jt*64 + wcol;
            #pragma unroll
            for (int q = 0; q < 2; ++q) {
                float4 v;
                if (k < kend) v = *reinterpret_cast<const float4*>(wsrc + q*4);
                else v = float4{0.f,0.f,0.f,0.f};
                *reinterpret_cast<float4*>(&ws_[wrow*68 + wcol + q*4]) = v;
            }
        }
        __syncthreads();
        #pragma unroll
        for (int kk = 0; kk < 32; ++kk) {
            float4 w4 = *reinterpret_cast<const float4*>(&ws_[kk*68 + tj*4]);
            float zv[4], wv[4] = {w4.x, w4.y, w4.z, w4.w};
            #pragma unroll
            for (int ib = 0; ib < 4; ++ib) zv[ib] = zs[(tb*4+ib)*36 + kk];
            #pragma unroll
            for (int ib = 0; ib < 4; ++ib)
                #pragma unroll
                for (int ij = 0; ij < 4; ++ij)
                    acc[ib][ij] = fmaf(zv[ib], wv[ij], acc[ib][ij]);
        }
        __syncthreads();
    }
    #pragma unroll
    for (int ib = 0; ib < 4; ++ib) {
        int row = bt*64 + tb*4 + ib;
        float4 v = make_float4(acc[ib][0], acc[ib][1], acc[ib][2], acc[ib][3]);
        *reinterpret_cast<float4*>(
            &out1_part[((size_t)ks*256 + row)*HH1 + jt*64 + tj*4]) = v;
    }
}

// ------------- tail: sum partials -> bn-relu -> FC2 -> bn-relu -> dot -------------
__global__ __launch_bounds__(256)
void k_tail_part(const float* __restrict__ out1_part,
            const float* __restrict__ fc_b1, const float* __restrict__ fbn1_g,
            const float* __restrict__ fbn1_b,
            const float* __restrict__ W2, const float* __restrict__ fc_b2,
            const float* __restrict__ fbn2_g, const float* __restrict__ fbn2_b,
            const float* __restrict__ fc1_w, const float* __restrict__ fc1_b,
            float* __restrict__ out)
{
    __shared__ float o1s[HH1];
    const int b = blockIdx.x, t = threadIdx.x;
    float raw = fc_b1[t];
    #pragma unroll 4
    for (int ks = 0; ks < 31; ++ks)
        raw += out1_part[((size_t)ks*256 + b)*HH1 + t];
    o1s[t] = fmaxf(raw * (BN_SCALE * fbn1_g[t]) + fbn1_b[t], 0.f);
    __syncthreads();
    if (t < HH2) {
        float acc = fc_b2[t];
        #pragma unroll 4
        for (int j = 0; j < HH1; ++j) acc = fmaf(o1s[j], W2[j*HH2 + t], acc);
        float v2 = fmaxf(acc * (BN_SCALE * fbn2_g[t]) + fbn2_b[t], 0.f);
        float c = v2 * fc1_w[t];
        #pragma unroll
        for (int off = 32; off; off >>= 1) c += __shfl_down(c, off);
        if (t == 0) out[b] = c + fc1_b[0];
    }
}

// =================== fallback path (round-1, proven; used if ws too small) ===================
__global__ __launch_bounds__(256)
void k_edge(const int* __restrict__ src, const int* __restrict__ dst,
            const float* __restrict__ ew, const float* __restrict__ x,
            float* __restrict__ agg)
{
    int i = blockIdx.x * 256 + threadIdx.x;
    const int4   s4 = reinterpret_cast<const int4*>(src)[i];
    const int4   d4 = reinterpret_cast<const int4*>(dst)[i];
    const float4 w4 = reinterpret_cast<const float4*>(ew)[i];
    unsafeAtomicAdd(&agg[d4.x], x[s4.x] * w4.x);
    unsafeAtomicAdd(&agg[d4.y], x[s4.y] * w4.y);
    unsafeAtomicAdd(&agg[d4.z], x[s4.z] * w4.z);
    unsafeAtomicAdd(&agg[d4.w], x[s4.w] * w4.w);
}

__global__ __launch_bounds__(256)
void k_sample(const float* __restrict__ x, const float* __restrict__ agg,
              const float* __restrict__ w_root, const float* __restrict__ w_rel,
              const float* __restrict__ b_rel,
              const float* __restrict__ ln_g, const float* __restrict__ ln_b,
              const float* __restrict__ gc1_w, const float* __restrict__ gc1_b,
              const float* __restrict__ bn1_g, const float* __restrict__ bn1_b,
              const float* __restrict__ gc2_w, const float* __restrict__ gc2_b,
              const float* __restrict__ bn2_g, const float* __restrict__ bn2_b,
              float* __restrict__ z)
{
    __shared__ float xs[NN], as[NN];
    __shared__ float gw1[CC1*MM], gb1[CC1], sb1[CC1], tb1[CC1];
    __shared__ float gw2[CC2*CC1], gb2[CC2], sb2[CC2], tb2[CC2];
    __shared__ float redS[4], redQ[4];
    __shared__ float s_mu, s_rs;

    const int b = blockIdx.x, t = threadIdx.x;
    const float* xb = x + b*NN;
    const float* ab = agg + b*NN;
    for (int n = t; n < NN; n += 256) { xs[n] = xb[n]; as[n] = ab[n]; }
    if (t < CC1*MM) gw1[t] = gc1_w[t];
    if (t >= 192 && t < 192+CC1) { int o = t-192; gb1[o]=gc1_b[o]; sb1[o]=BN_SCALE*bn1_g[o]; tb1[o]=bn1_b[o]; }
    if (t >= 208 && t < 208+CC2*CC1) gw2[t-208] = gc2_w[t-208];
    if (t >= 240 && t < 240+CC2) { int p=t-240; gb2[p]=gc2_b[p]; sb2[p]=BN_SCALE*bn2_g[p]; tb2[p]=bn2_b[p]; }

    float wr[MM], br[MM], wo[MM];
    #pragma unroll
    for (int m = 0; m < MM; ++m) { wr[m]=w_rel[m]; br[m]=b_rel[m]; wo[m]=w_root[m]; }
    __syncthreads();

    float S = 0.f, Q = 0.f;
    for (int n = t; n < NN; n += 256) {
        float a = as[n], xv = xs[n];
        #pragma unroll
        for (int m = 0; m < MM; ++m) {
            float h = fmaxf(fmaf(a, wr[m], fmaf(xv, wo[m], br[m])), 0.f);
            S += h; Q += h*h;
        }
    }
    #pragma unroll
    for (int off = 32; off; off >>= 1) { S += __shfl_down(S, off); Q += __shfl_down(Q, off); }
    if ((t & 63) == 0) { redS[t>>6] = S; redQ[t>>6] = Q; }
    __syncthreads();
    if (t == 0) {
        float SS = redS[0]+redS[1]+redS[2]+redS[3];
        float QQ = redQ[0]+redQ[1]+redQ[2]+redQ[3];
        const float inv = 1.f / (float)(NN*MM);
        float mu = SS * inv;
        float var = QQ * inv - mu*mu;
        s_mu = mu; s_rs = rsqrtf(var + LN_EPS);
    }
    __syncthreads();
    const float mu = s_mu, rs = s_rs;

    float* zb = z + (size_t)b * KK1;
    for (int n = t; n < NN; n += 256) {
        float a = as[n], xv = xs[n];
        float hn[MM];
        const float4* g4  = reinterpret_cast<const float4*>(ln_g + n*MM);
        const float4* be4 = reinterpret_cast<const float4*>(ln_b + n*MM);
        #pragma unroll
        for (int q = 0; q < 4; ++q) {
            float4 g = g4[q], be = be4[q];
            float gg[4]  = {g.x, g.y, g.z, g.w};
            float bb_[4] = {be.x, be.y, be.z, be.w};
            #pragma unroll
            for (int j = 0; j < 4; ++j) {
                int m = q*4 + j;
                float h = fmaxf(fmaf(a, wr[m], fmaf(xv, wo[m], br[m])), 0.f);
                hn[m] = (h - mu) * rs * gg[j] + bb_[j];
            }
        }
        float y1[CC1];
        #pragma unroll
        for (int o = 0; o < CC1; ++o) {
            float a1 = gb1[o];
            #pragma unroll
            for (int m = 0; m < MM; ++m) a1 = fmaf(gw1[o*MM+m], hn[m], a1);
            y1[o] = fmaxf(a1, 0.f) * sb1[o] + tb1[o];
        }
        #pragma unroll
        for (int p = 0; p < CC2; ++p) {
            float a2 = gb2[p];
            #pragma unroll
            for (int o = 0; o < CC1; ++o) a2 = fmaf(gw2[p*CC1+o], y1[o], a2);
            zb[p*NN + n] = fmaxf(a2, 0.f) * sb2[p] + tb2[p];
        }
    }
}

__global__ __launch_bounds__(256)
void k_fc1(const float* __restrict__ z, const float* __restrict__ W1,
           float* __restrict__ out1_raw)
{
    __shared__ float zs[64*36];
    __shared__ float ws_[32*68];
    const int bt = blockIdx.x, jt = blockIdx.y, ks = blockIdx.z;
    const int t = threadIdx.x;
    const int tb = t >> 4, tj = t & 15;
    const int k0 = ks * GK_CHUNK;
    const int kend = min(k0 + GK_CHUNK, KK1);
    float acc[4][4] = {};
    const int zrow = t >> 2, zcol = (t & 3) * 8;
    const int wrow = t >> 3, wcol = (t & 7) * 8;

    for (int kc = k0; kc < kend; kc += 32) {
        const float* zsrc = z + (size_t)(bt*64 + zrow)*KK1 + kc + zcol;
        #pragma unroll
        for (int q = 0; q < 2; ++q) {
            int k = kc + zcol + q*4;
            float4 v;
            if (k + 3 < kend) v = *reinterpret_cast<const float4*>(zsrc + q*4);
            else {
                v.x = (k+0 < kend) ? zsrc[q*4+0] : 0.f;
                v.y = (k+1 < kend) ? zsrc[q*4+1] : 0.f;
                v.z = (k+2 < kend) ? zsrc[q*4+2] : 0.f;
                v.w = (k+3 < kend) ? zsrc[q*4+3] : 0.f;
            }
            *reinterpret_cast<float4*>(&zs[zrow*36 + zcol + q*4]) = v;
        }
        {
            int k = kc + wrow;
            const float* wsrc = W1 + (size_t)k*HH1 + jt*64 + wcol;
            #pragma unroll
            for (int q = 0; q < 2; ++q) {
                float4 v;
                if (k < kend) v = *reinterpret_cast<const float4*>(wsrc + q*4);
                else v = float4{0.f,0.f,0.f,0.f};
                *reinterpret_cast<float4*>(&ws_[wrow*68 + wcol + q*4]) = v;
            }
        }
        __syncthreads();
        #pragma unroll
        for (int kk = 0; kk < 32; ++kk) {
            float4 w4 = *reinterpret_cast<const float4*>(&ws_[kk*68 + tj*4]);
            float zv[4], wv[4] = {w4.x, w4.y, w4.z, w4.w};
            #pragma unroll
            for (int ib = 0; ib < 4; ++ib) zv[ib] = zs[(tb*4+ib)*36 + kk];
            #pragma unroll
            for (int ib = 0; ib < 4; ++ib)
                #pragma unroll
                for (int ij = 0; ij < 4; ++ij)
                    acc[ib][ij] = fmaf(zv[ib], wv[ij], acc[ib][ij]);
        }
        __syncthreads();
    }
    #pragma unroll
    for (int ib = 0; ib < 4; ++ib) {
        int row = bt*64 + tb*4 + ib;
        #pragma unroll
        for (int ij = 0; ij < 4; ++ij)
            unsafeAtomicAdd(&out1_raw[row*HH1 + jt*64 + tj*4 + ij], acc[ib][ij]);
    }
}

__global__ __launch_bounds__(256)
void k_tail(const float* __restrict__ out1_raw,
            const float* __restrict__ fc_b1, const float* __restrict__ fbn1_g,
            const float* __restrict__ fbn1_b,
            const float* __restrict__ W2, const float* __restrict__ fc_b2,
            const float* __restrict__ fbn2_g, const float* __restrict__ fbn2_b,
            const float* __restrict__ fc1_w, const float* __restrict__ fc1_b,
            float* __restrict__ out)
{
    __shared__ float o1s[HH1];
    const int b = blockIdx.x, t = threadIdx.x;
    float raw = out1_raw[b*HH1 + t] + fc_b1[t];
    o1s[t] = fmaxf(raw * (BN_SCALE * fbn1_g[t]) + fbn1_b[t], 0.f);
    __syncthreads();
    if (t < HH2) {
        float acc = fc_b2[t];
        #pragma unroll 4
        for (int j = 0; j < HH1; ++j) acc = fmaf(o1s[j], W2[j*HH2 + t], acc);
        float v2 = fmaxf(acc * (BN_SCALE * fbn2_g[t]) + fbn2_b[t], 0.f);
        float c = v2 * fc1_w[t];
        #pragma unroll
        for (int off = 32; off; off >>= 1) c += __shfl_down(c, off);
        if (t == 0) out[b] = c + fc1_b[0];
    }
}

extern "C" void kernel_launch(void* const* d_in, const int* in_sizes, int n_in,
                              void* d_out, int out_size, void* d_ws, size_t ws_size,
                              hipStream_t stream)
{
    const float* x      = (const float*)d_in[0];
    const int*   ei     = (const int*)  d_in[1];
    const float* ew     = (const float*)d_in[2];
    const float* w_root = (const float*)d_in[3];
    const float* w_rel  = (const float*)d_in[4];
    const float* b_rel  = (const float*)d_in[5];
    const float* ln_g   = (const float*)d_in[6];
    const float* ln_b   = (const float*)d_in[7];
    const float* gc1_w  = (const float*)d_in[8];
    const float* gc1_b  = (const float*)d_in[9];
    const float* bn1_g  = (const float*)d_in[10];
    const float* bn1_b  = (const float*)d_in[11];
    const float* gc2_w  = (const float*)d_in[12];
    const float* gc2_b  = (const float*)d_in[13];
    const float* bn2_g  = (const float*)d_in[14];
    const float* bn2_b  = (const float*)d_in[15];
    const float* fc_w1  = (const float*)d_in[16];
    const float* fc_b1  = (const float*)d_in[17];
    const float* fbn1_g = (const float*)d_in[18];
    const float* fbn1_b = (const float*)d_in[19];
    const float* fc_w2  = (const float*)d_in[20];
    const float* fc_b2  = (const float*)d_in[21];
    const float* fbn2_g = (const float*)d_in[22];
    const float* fbn2_b = (const float*)d_in[23];
    const float* fc1_w  = (const float*)d_in[24];
    const float* fc1_b  = (const float*)d_in[25];
    float* out = (float*)d_out;

    char* ws = (char*)d_ws;
    // layout: recs | stab | paggr (reused as o1p) | zbuf
    const size_t off_recs  = 0;                                   // 4096*4096*8 = 134,217,728
    const size_t off_stab  = off_recs + (size_t)NBLK*EPB*8;       // +2,097,152
    const size_t off_paggr = off_stab + (size_t)NBLK*NBK*2;
    const size_t o1p_sz    = (size_t)31*HH1*256*4;                // 8,126,464

    // pick largest rspl whose layout fits
    int rspl = 8;
    size_t pg_sz   = (size_t)rspl*NBK*NN*4;
    if (pg_sz < o1p_sz) pg_sz = o1p_sz;
    size_t off_zbuf = off_paggr + pg_sz;
    size_t need     = off_zbuf + (size_t)BB*KK1*4;
    if (ws_size < need) {
        rspl = 4;
        pg_sz = (size_t)rspl*NBK*NN*4;            // 9,039,872 >= o1p_sz
        off_zbuf = off_paggr + pg_sz;
        need = off_zbuf + (size_t)BB*KK1*4;       // 154.4 MB, proven
    }

    if (ws_size >= need) {
        uint2*          recs  = (uint2*)(ws + off_recs);
        unsigned short* stab  = (unsigned short*)(ws + off_stab);
        float*          paggr = (float*)(ws + off_paggr);
        float*          zbuf  = (float*)(ws + off_zbuf);
        float*          o1p   = (float*)(ws + off_paggr);  // reused after k_ln_conv

        k_place2<<<NBLK, TPB, 0, stream>>>(ei, ei + EE, ew, x, recs, stab);
        k_replay2<<<NBK*rspl, RTPB, 0, stream>>>(recs, stab, paggr, rspl);
        k_ln_conv<<<BB, 512, 0, stream>>>(x, paggr,
                                         w_root, w_rel, b_rel, ln_g, ln_b,
                                         gc1_w, gc1_b, bn1_g, bn1_b,
                                         gc2_w, gc2_b, bn2_g, bn2_b, zbuf, rspl);
        k_fc1_part<<<dim3(4,4,31), 256, 0, stream>>>(zbuf, fc_w1, o1p);
        k_tail_part<<<BB, 256, 0, stream>>>(o1p, fc_b1, fbn1_g, fbn1_b,
                                       fc_w2, fc_b2, fbn2_g, fbn2_b,
                                       fc1_w, fc1_b, out);
    } else {
        // round-1 fallback (proven <= 11.6 MB ws)
        float* agg      = (float*)(ws);
        float* zbuf     = (float*)(ws + 2259968);
        float* out1_raw = (float*)(ws + 2259968 + 9039872);

        hipMemsetAsync(agg,      0, (size_t)BB*NN*sizeof(float),  stream);
        hipMemsetAsync(out1_raw, 0, (size_t)BB*HH1*sizeof(float), stream);

        k_edge<<<EE/4/256, 256, 0, stream>>>(ei, ei + EE, ew, x, agg);
        k_sample<<<BB, 256, 0, stream>>>(x, agg, w_root, w_rel, b_rel, ln_g, ln_b,
                                         gc1_w, gc1_b, bn1_g, bn1_b,
                                         gc2_w, gc2_b, bn2_g, bn2_b, zbuf);
        k_fc1<<<dim3(4,4,31), 256, 0, stream>>>(zbuf, fc_w1, out1_raw);
        k_tail<<<BB, 256, 0, stream>>>(out1_raw, fc_b1, fbn1_g, fbn1_b,
                                       fc_w2, fc_b2, fbn2_g, fbn2_b,
                                       fc1_w, fc1_b, out);
    }
}

// Round 9
// 314.505 us; speedup vs baseline: 1.5762x; 1.1010x over previous
//
#include <hip/hip_runtime.h>
#include <hip/hip_bf16.h>

#define BB   256
#define NN   2207
#define MM   16
#define EE   16777216
#define CC1  12
#define CC2  4
#define HH1  256
#define HH2  64
#define KK1  (CC2*NN)          /* 8828 */
#define LN_EPS 1e-5f
#define BN_SCALE 0.9999950000374997f   /* 1/sqrt(1+1e-5) */
#define NBK  256               /* buckets == samples */
#define MAGIC 1946067ull       /* ceil(2^32/2207), exact for d < 564992 */
#define EPB  4096              /* edges per bin block */
#define TPB  512
#define EPT  (EPB/TPB)         /* 8 edges per thread */
#define NBLK (EE/EPB)          /* 4096 bin blocks */

static __device__ __forceinline__ unsigned bucket_of(int d) {
    return (unsigned)(((unsigned long long)(unsigned)d * MAGIC) >> 32);
}

// ===== PASS 1: rank + scan + DIRECT global scatter (no x-gather, no LDS staging) =====
// record = ( src<<12 | dst_local , w )  -- gather deferred to replay
__global__ __launch_bounds__(TPB, 8)
void k_place4(const int* __restrict__ src, const int* __restrict__ dst,
              const float* __restrict__ ew,
              uint2* __restrict__ recs, unsigned short* __restrict__ stab)
{
    __shared__ unsigned int hist[NBK], start[NBK];
    __shared__ unsigned int wtot[4];

    const int t = threadIdx.x;
    if (t < NBK) hist[t] = 0;
    __syncthreads();

    const int i4base = blockIdx.x * (EPB/4);
    unsigned key[EPT];           // (src<<12) | dst_local
    float    wv[EPT];
    unsigned short rk[EPT];      // intra-bucket rank < 4096
    unsigned char  bk[EPT];      // bucket
    #pragma unroll
    for (int q = 0; q < EPT/4; ++q) {
        int i4 = i4base + q*TPB + t;
        int4   s4 = reinterpret_cast<const int4*>(src)[i4];
        int4   d4 = reinterpret_cast<const int4*>(dst)[i4];
        float4 w4 = reinterpret_cast<const float4*>(ew)[i4];
        unsigned b0 = bucket_of(d4.x), b1 = bucket_of(d4.y);
        unsigned b2 = bucket_of(d4.z), b3 = bucket_of(d4.w);
        unsigned r0 = atomicAdd(&hist[b0], 1u);
        unsigned r1 = atomicAdd(&hist[b1], 1u);
        unsigned r2 = atomicAdd(&hist[b2], 1u);
        unsigned r3 = atomicAdd(&hist[b3], 1u);
        key[q*4+0] = ((unsigned)s4.x << 12) | (unsigned)(d4.x - (int)(b0*NN));
        key[q*4+1] = ((unsigned)s4.y << 12) | (unsigned)(d4.y - (int)(b1*NN));
        key[q*4+2] = ((unsigned)s4.z << 12) | (unsigned)(d4.z - (int)(b2*NN));
        key[q*4+3] = ((unsigned)s4.w << 12) | (unsigned)(d4.w - (int)(b3*NN));
        wv[q*4+0] = w4.x; wv[q*4+1] = w4.y; wv[q*4+2] = w4.z; wv[q*4+3] = w4.w;
        rk[q*4+0] = (unsigned short)r0; rk[q*4+1] = (unsigned short)r1;
        rk[q*4+2] = (unsigned short)r2; rk[q*4+3] = (unsigned short)r3;
        bk[q*4+0] = (unsigned char)b0; bk[q*4+1] = (unsigned char)b1;
        bk[q*4+2] = (unsigned char)b2; bk[q*4+3] = (unsigned char)b3;
    }
    __syncthreads();

    // exclusive prefix scan of hist[256] (4 waves of 64)
    if (t < NBK) {
        unsigned h = hist[t], v = h;
        #pragma unroll
        for (int off = 1; off < 64; off <<= 1) {
            unsigned u = __shfl_up(v, off);
            if ((t & 63) >= off) v += u;
        }
        start[t] = v - h;
        if ((t & 63) == 63) wtot[t >> 6] = v;
    }
    __syncthreads();
    if (t < NBK) {
        const int w = t >> 6;
        unsigned wo = 0;
        if (w > 0) wo += wtot[0];
        if (w > 1) wo += wtot[1];
        if (w > 2) wo += wtot[2];
        start[t] += wo;
        stab[blockIdx.x * NBK + t] = (unsigned short)(start[t]);
    }
    __syncthreads();

    // direct scatter to the block-private 32 KB region (L2 merges the 8B writes)
    uint2* rb = recs + (size_t)blockIdx.x * EPB;
    #pragma unroll
    for (int e = 0; e < EPT; ++e)
        rb[start[bk[e]] + (unsigned)rk[e]] =
            make_uint2(key[e], __float_as_uint(wv[e]));
}

// ===== PASS 2a: group-run replay with deferred gather -> partial agg =====
#define RTPB 256
__global__ __launch_bounds__(RTPB, 8)
void k_replay3(const uint2* __restrict__ recs, const unsigned short* __restrict__ stab,
               const float* __restrict__ x, float* __restrict__ paggr, int rspl)
{
    __shared__ float acc[NN];
    const int t = threadIdx.x;
    const int j = blockIdx.x & (NBK - 1);       // sample
    const int r = blockIdx.x >> 8;              // split index 0..rspl-1
    const int kpr = NBLK / rspl;                // bin-blocks per replay block
    for (int n = t; n < NN; n += RTPB) acc[n] = 0.f;
    __syncthreads();

    const int gid = t >> 4, l16 = t & 15;       // 16 groups of 16 lanes
    const int kb0 = r * kpr;
    for (int kb_i = gid; kb_i < kpr; kb_i += RTPB/16) {
        const int kb = kb0 + kb_i;
        unsigned s0 = stab[(size_t)kb * NBK + j];
        unsigned s1 = (j < NBK-1) ? (unsigned)stab[(size_t)kb * NBK + j + 1]
                                  : (unsigned)EPB;
        const uint2* rp = recs + (size_t)kb * EPB;
        for (unsigned u = s0 + (unsigned)l16; u < s1; u += 16u) {
            uint2 rec = rp[u];
            atomicAdd(&acc[rec.x & 0xFFFu],
                      x[rec.x >> 12] * __uint_as_float(rec.y));
        }
    }
    __syncthreads();
    float* pa = paggr + ((size_t)r * NBK + j) * NN;
    for (int n = t; n < NN; n += RTPB) pa[n] = acc[n];
}

// ===== PASS 2b: sum partials + relu/LN/conv1/bn/conv2/bn -> z =====
__global__ __launch_bounds__(512)
void k_ln_conv(const float* __restrict__ x, const float* __restrict__ paggr,
              const float* __restrict__ w_root, const float* __restrict__ w_rel,
              const float* __restrict__ b_rel,
              const float* __restrict__ ln_g, const float* __restrict__ ln_b,
              const float* __restrict__ gc1_w, const float* __restrict__ gc1_b,
              const float* __restrict__ bn1_g, const float* __restrict__ bn1_b,
              const float* __restrict__ gc2_w, const float* __restrict__ gc2_b,
              const float* __restrict__ bn2_g, const float* __restrict__ bn2_b,
              float* __restrict__ z, int rspl)
{
    __shared__ float xs[NN], acc[NN];
    __shared__ float gw1[CC1*MM], gb1[CC1], sb1[CC1], tb1[CC1];
    __shared__ float gw2[CC2*CC1], gb2[CC2], sb2[CC2], tb2[CC2];
    __shared__ float redS[8], redQ[8];
    __shared__ float s_mu, s_rs;

    const int b = blockIdx.x, t = threadIdx.x;
    const float* xb = x + b*NN;
    for (int n = t; n < NN; n += 512) {
        xs[n] = xb[n];
        float a = 0.f;
        for (int r = 0; r < rspl; ++r)
            a += paggr[((size_t)r * NBK + b) * NN + n];
        acc[n] = a;
    }
    if (t < CC1*MM) gw1[t] = gc1_w[t];
    if (t >= 192 && t < 192+CC1) { int o = t-192; gb1[o]=gc1_b[o]; sb1[o]=BN_SCALE*bn1_g[o]; tb1[o]=bn1_b[o]; }
    if (t >= 208 && t < 208+CC2*CC1) gw2[t-208] = gc2_w[t-208];
    if (t >= 240 && t < 240+CC2) { int p=t-240; gb2[p]=gc2_b[p]; sb2[p]=BN_SCALE*bn2_g[p]; tb2[p]=bn2_b[p]; }

    float wr[MM], br[MM], wo[MM];
    #pragma unroll
    for (int m = 0; m < MM; ++m) { wr[m]=w_rel[m]; br[m]=b_rel[m]; wo[m]=w_root[m]; }
    __syncthreads();

    // LN statistics over (N, M)
    float S = 0.f, Q = 0.f;
    for (int n = t; n < NN; n += 512) {
        float a = acc[n], xv = xs[n];
        #pragma unroll
        for (int m = 0; m < MM; ++m) {
            float h = fmaxf(fmaf(a, wr[m], fmaf(xv, wo[m], br[m])), 0.f);
            S += h; Q += h*h;
        }
    }
    #pragma unroll
    for (int off = 32; off; off >>= 1) { S += __shfl_down(S, off); Q += __shfl_down(Q, off); }
    if ((t & 63) == 0) { redS[t>>6] = S; redQ[t>>6] = Q; }
    __syncthreads();
    if (t == 0) {
        float SS = 0.f, QQ = 0.f;
        #pragma unroll
        for (int i = 0; i < 8; ++i) { SS += redS[i]; QQ += redQ[i]; }
        const float inv = 1.f / (float)(NN*MM);
        float mu = SS * inv;
        float var = QQ * inv - mu*mu;
        s_mu = mu; s_rs = rsqrtf(var + LN_EPS);
    }
    __syncthreads();
    const float mu = s_mu, rs = s_rs;

    float* zb = z + (size_t)b * KK1;
    for (int n = t; n < NN; n += 512) {
        float a = acc[n], xv = xs[n];
        float hn[MM];
        const float4* g4  = reinterpret_cast<const float4*>(ln_g + n*MM);
        const float4* be4 = reinterpret_cast<const float4*>(ln_b + n*MM);
        #pragma unroll
        for (int q = 0; q < 4; ++q) {
            float4 g = g4[q], be = be4[q];
            float gg[4]  = {g.x, g.y, g.z, g.w};
            float bb_[4] = {be.x, be.y, be.z, be.w};
            #pragma unroll
            for (int j = 0; j < 4; ++j) {
                int m = q*4 + j;
                float h = fmaxf(fmaf(a, wr[m], fmaf(xv, wo[m], br[m])), 0.f);
                hn[m] = (h - mu) * rs * gg[j] + bb_[j];
            }
        }
        float y1[CC1];
        #pragma unroll
        for (int o = 0; o < CC1; ++o) {
            float a1 = gb1[o];
            #pragma unroll
            for (int m = 0; m < MM; ++m) a1 = fmaf(gw1[o*MM+m], hn[m], a1);
            y1[o] = fmaxf(a1, 0.f) * sb1[o] + tb1[o];
        }
        #pragma unroll
        for (int p = 0; p < CC2; ++p) {
            float a2 = gb2[p];
            #pragma unroll
            for (int o = 0; o < CC1; ++o) a2 = fmaf(gw2[p*CC1+o], y1[o], a2);
            zb[p*NN + n] = fmaxf(a2, 0.f) * sb2[p] + tb2[p];
        }
    }
}

// ------------- FC1 GEMM: split-K partials (no atomics) -------------
#define GK_CHUNK 288   /* grid.z = 31; 31*288 = 8928 >= 8828 */
__global__ __launch_bounds__(256)
void k_fc1_part(const float* __restrict__ z, const float* __restrict__ W1,
                float* __restrict__ out1_part)
{
    __shared__ float zs[64*36];
    __shared__ float ws_[32*68];
    const int bt = blockIdx.x, jt = blockIdx.y, ks = blockIdx.z;
    const int t = threadIdx.x;
    const int tb = t >> 4, tj = t & 15;
    const int k0 = ks * GK_CHUNK;
    const int kend = min(k0 + GK_CHUNK, KK1);
    float acc[4][4] = {};
    const int zrow = t >> 2, zcol = (t & 3) * 8;
    const int wrow = t >> 3, wcol = (t & 7) * 8;

    for (int kc = k0; kc < kend; kc += 32) {
        const float* zsrc = z + (size_t)(bt*64 + zrow)*KK1 + kc + zcol;
        #pragma unroll
        for (int q = 0; q < 2; ++q) {
            int k = kc + zcol + q*4;
            float4 v;
            if (k + 3 < kend) v = *reinterpret_cast<const float4*>(zsrc + q*4);
            else {
                v.x = (k+0 < kend) ? zsrc[q*4+0] : 0.f;
                v.y = (k+1 < kend) ? zsrc[q*4+1] : 0.f;
                v.z = (k+2 < kend) ? zsrc[q*4+2] : 0.f;
                v.w = (k+3 < kend) ? zsrc[q*4+3] : 0.f;
            }
            *reinterpret_cast<float4*>(&zs[zrow*36 + zcol + q*4]) = v;
        }
        {
            int k = kc + wrow;
            const float* wsrc = W1 + (size_t)k*HH1 + jt*64 + wcol;
            #pragma unroll
            for (int q = 0; q < 2; ++q) {
                float4 v;
                if (k < kend) v = *reinterpret_cast<const float4*>(wsrc + q*4);
                else v = float4{0.f,0.f,0.f,0.f};
                *reinterpret_cast<float4*>(&ws_[wrow*68 + wcol + q*4]) = v;
            }
        }
        __syncthreads();
        #pragma unroll
        for (int kk = 0; kk < 32; ++kk) {
            float4 w4 = *reinterpret_cast<const float4*>(&ws_[kk*68 + tj*4]);
            float zv[4], wv[4] = {w4.x, w4.y, w4.z, w4.w};
            #pragma unroll
            for (int ib = 0; ib < 4; ++ib) zv[ib] = zs[(tb*4+ib)*36 + kk];
            #pragma unroll
            for (int ib = 0; ib < 4; ++ib)
                #pragma unroll
                for (int ij = 0; ij < 4; ++ij)
                    acc[ib][ij] = fmaf(zv[ib], wv[ij], acc[ib][ij]);
        }
        __syncthreads();
    }
    #pragma unroll
    for (int ib = 0; ib < 4; ++ib) {
        int row = bt*64 + tb*4 + ib;
        float4 v = make_float4(acc[ib][0], acc[ib][1], acc[ib][2], acc[ib][3]);
        *reinterpret_cast<float4*>(
            &out1_part[((size_t)ks*256 + row)*HH1 + jt*64 + tj*4]) = v;
    }
}

// ------------- tail: sum partials -> bn-relu -> FC2 -> bn-relu -> dot -------------
__global__ __launch_bounds__(256)
void k_tail_part(const float* __restrict__ out1_part,
            const float* __restrict__ fc_b1, const float* __restrict__ fbn1_g,
            const float* __restrict__ fbn1_b,
            const float* __restrict__ W2, const float* __restrict__ fc_b2,
            const float* __restrict__ fbn2_g, const float* __restrict__ fbn2_b,
            const float* __restrict__ fc1_w, const float* __restrict__ fc1_b,
            float* __restrict__ out)
{
    __shared__ float o1s[HH1];
    const int b = blockIdx.x, t = threadIdx.x;
    float raw = fc_b1[t];
    #pragma unroll 4
    for (int ks = 0; ks < 31; ++ks)
        raw += out1_part[((size_t)ks*256 + b)*HH1 + t];
    o1s[t] = fmaxf(raw * (BN_SCALE * fbn1_g[t]) + fbn1_b[t], 0.f);
    __syncthreads();
    if (t < HH2) {
        float acc = fc_b2[t];
        #pragma unroll 4
        for (int j = 0; j < HH1; ++j) acc = fmaf(o1s[j], W2[j*HH2 + t], acc);
        float v2 = fmaxf(acc * (BN_SCALE * fbn2_g[t]) + fbn2_b[t], 0.f);
        float c = v2 * fc1_w[t];
        #pragma unroll
        for (int off = 32; off; off >>= 1) c += __shfl_down(c, off);
        if (t == 0) out[b] = c + fc1_b[0];
    }
}

// =================== fallback path (round-1, proven; used if ws too small) ===================
__global__ __launch_bounds__(256)
void k_edge(const int* __restrict__ src, const int* __restrict__ dst,
            const float* __restrict__ ew, const float* __restrict__ x,
            float* __restrict__ agg)
{
    int i = blockIdx.x * 256 + threadIdx.x;
    const int4   s4 = reinterpret_cast<const int4*>(src)[i];
    const int4   d4 = reinterpret_cast<const int4*>(dst)[i];
    const float4 w4 = reinterpret_cast<const float4*>(ew)[i];
    unsafeAtomicAdd(&agg[d4.x], x[s4.x] * w4.x);
    unsafeAtomicAdd(&agg[d4.y], x[s4.y] * w4.y);
    unsafeAtomicAdd(&agg[d4.z], x[s4.z] * w4.z);
    unsafeAtomicAdd(&agg[d4.w], x[s4.w] * w4.w);
}

__global__ __launch_bounds__(256)
void k_sample(const float* __restrict__ x, const float* __restrict__ agg,
              const float* __restrict__ w_root, const float* __restrict__ w_rel,
              const float* __restrict__ b_rel,
              const float* __restrict__ ln_g, const float* __restrict__ ln_b,
              const float* __restrict__ gc1_w, const float* __restrict__ gc1_b,
              const float* __restrict__ bn1_g, const float* __restrict__ bn1_b,
              const float* __restrict__ gc2_w, const float* __restrict__ gc2_b,
              const float* __restrict__ bn2_g, const float* __restrict__ bn2_b,
              float* __restrict__ z)
{
    __shared__ float xs[NN], as[NN];
    __shared__ float gw1[CC1*MM], gb1[CC1], sb1[CC1], tb1[CC1];
    __shared__ float gw2[CC2*CC1], gb2[CC2], sb2[CC2], tb2[CC2];
    __shared__ float redS[4], redQ[4];
    __shared__ float s_mu, s_rs;

    const int b = blockIdx.x, t = threadIdx.x;
    const float* xb = x + b*NN;
    const float* ab = agg + b*NN;
    for (int n = t; n < NN; n += 256) { xs[n] = xb[n]; as[n] = ab[n]; }
    if (t < CC1*MM) gw1[t] = gc1_w[t];
    if (t >= 192 && t < 192+CC1) { int o = t-192; gb1[o]=gc1_b[o]; sb1[o]=BN_SCALE*bn1_g[o]; tb1[o]=bn1_b[o]; }
    if (t >= 208 && t < 208+CC2*CC1) gw2[t-208] = gc2_w[t-208];
    if (t >= 240 && t < 240+CC2) { int p=t-240; gb2[p]=gc2_b[p]; sb2[p]=BN_SCALE*bn2_g[p]; tb2[p]=bn2_b[p]; }

    float wr[MM], br[MM], wo[MM];
    #pragma unroll
    for (int m = 0; m < MM; ++m) { wr[m]=w_rel[m]; br[m]=b_rel[m]; wo[m]=w_root[m]; }
    __syncthreads();

    float S = 0.f, Q = 0.f;
    for (int n = t; n < NN; n += 256) {
        float a = as[n], xv = xs[n];
        #pragma unroll
        for (int m = 0; m < MM; ++m) {
            float h = fmaxf(fmaf(a, wr[m], fmaf(xv, wo[m], br[m])), 0.f);
            S += h; Q += h*h;
        }
    }
    #pragma unroll
    for (int off = 32; off; off >>= 1) { S += __shfl_down(S, off); Q += __shfl_down(Q, off); }
    if ((t & 63) == 0) { redS[t>>6] = S; redQ[t>>6] = Q; }
    __syncthreads();
    if (t == 0) {
        float SS = redS[0]+redS[1]+redS[2]+redS[3];
        float QQ = redQ[0]+redQ[1]+redQ[2]+redQ[3];
        const float inv = 1.f / (float)(NN*MM);
        float mu = SS * inv;
        float var = QQ * inv - mu*mu;
        s_mu = mu; s_rs = rsqrtf(var + LN_EPS);
    }
    __syncthreads();
    const float mu = s_mu, rs = s_rs;

    float* zb = z + (size_t)b * KK1;
    for (int n = t; n < NN; n += 256) {
        float a = as[n], xv = xs[n];
        float hn[MM];
        const float4* g4  = reinterpret_cast<const float4*>(ln_g + n*MM);
        const float4* be4 = reinterpret_cast<const float4*>(ln_b + n*MM);
        #pragma unroll
        for (int q = 0; q < 4; ++q) {
            float4 g = g4[q], be = be4[q];
            float gg[4]  = {g.x, g.y, g.z, g.w};
            float bb_[4] = {be.x, be.y, be.z, be.w};
            #pragma unroll
            for (int j = 0; j < 4; ++j) {
                int m = q*4 + j;
                float h = fmaxf(fmaf(a, wr[m], fmaf(xv, wo[m], br[m])), 0.f);
                hn[m] = (h - mu) * rs * gg[j] + bb_[j];
            }
        }
        float y1[CC1];
        #pragma unroll
        for (int o = 0; o < CC1; ++o) {
            float a1 = gb1[o];
            #pragma unroll
            for (int m = 0; m < MM; ++m) a1 = fmaf(gw1[o*MM+m], hn[m], a1);
            y1[o] = fmaxf(a1, 0.f) * sb1[o] + tb1[o];
        }
        #pragma unroll
        for (int p = 0; p < CC2; ++p) {
            float a2 = gb2[p];
            #pragma unroll
            for (int o = 0; o < CC1; ++o) a2 = fmaf(gw2[p*CC1+o], y1[o], a2);
            zb[p*NN + n] = fmaxf(a2, 0.f) * sb2[p] + tb2[p];
        }
    }
}

__global__ __launch_bounds__(256)
void k_fc1(const float* __restrict__ z, const float* __restrict__ W1,
           float* __restrict__ out1_raw)
{
    __shared__ float zs[64*36];
    __shared__ float ws_[32*68];
    const int bt = blockIdx.x, jt = blockIdx.y, ks = blockIdx.z;
    const int t = threadIdx.x;
    const int tb = t >> 4, tj = t & 15;
    const int k0 = ks * GK_CHUNK;
    const int kend = min(k0 + GK_CHUNK, KK1);
    float acc[4][4] = {};
    const int zrow = t >> 2, zcol = (t & 3) * 8;
    const int wrow = t >> 3, wcol = (t & 7) * 8;

    for (int kc = k0; kc < kend; kc += 32) {
        const float* zsrc = z + (size_t)(bt*64 + zrow)*KK1 + kc + zcol;
        #pragma unroll
        for (int q = 0; q < 2; ++q) {
            int k = kc + zcol + q*4;
            float4 v;
            if (k + 3 < kend) v = *reinterpret_cast<const float4*>(zsrc + q*4);
            else {
                v.x = (k+0 < kend) ? zsrc[q*4+0] : 0.f;
                v.y = (k+1 < kend) ? zsrc[q*4+1] : 0.f;
                v.z = (k+2 < kend) ? zsrc[q*4+2] : 0.f;
                v.w = (k+3 < kend) ? zsrc[q*4+3] : 0.f;
            }
            *reinterpret_cast<float4*>(&zs[zrow*36 + zcol + q*4]) = v;
        }
        {
            int k = kc + wrow;
            const float* wsrc = W1 + (size_t)k*HH1 + jt*64 + wcol;
            #pragma unroll
            for (int q = 0; q < 2; ++q) {
                float4 v;
                if (k < kend) v = *reinterpret_cast<const float4*>(wsrc + q*4);
                else v = float4{0.f,0.f,0.f,0.f};
                *reinterpret_cast<float4*>(&ws_[wrow*68 + wcol + q*4]) = v;
            }
        }
        __syncthreads();
        #pragma unroll
        for (int kk = 0; kk < 32; ++kk) {
            float4 w4 = *reinterpret_cast<const float4*>(&ws_[kk*68 + tj*4]);
            float zv[4], wv[4] = {w4.x, w4.y, w4.z, w4.w};
            #pragma unroll
            for (int ib = 0; ib < 4; ++ib) zv[ib] = zs[(tb*4+ib)*36 + kk];
            #pragma unroll
            for (int ib = 0; ib < 4; ++ib)
                #pragma unroll
                for (int ij = 0; ij < 4; ++ij)
                    acc[ib][ij] = fmaf(zv[ib], wv[ij], acc[ib][ij]);
        }
        __syncthreads();
    }
    #pragma unroll
    for (int ib = 0; ib < 4; ++ib) {
        int row = bt*64 + tb*4 + ib;
        #pragma unroll
        for (int ij = 0; ij < 4; ++ij)
            unsafeAtomicAdd(&out1_raw[row*HH1 + jt*64 + tj*4 + ij], acc[ib][ij]);
    }
}

__global__ __launch_bounds__(256)
void k_tail(const float* __restrict__ out1_raw,
            const float* __restrict__ fc_b1, const float* __restrict__ fbn1_g,
            const float* __restrict__ fbn1_b,
            const float* __restrict__ W2, const float* __restrict__ fc_b2,
            const float* __restrict__ fbn2_g, const float* __restrict__ fbn2_b,
            const float* __restrict__ fc1_w, const float* __restrict__ fc1_b,
            float* __restrict__ out)
{
    __shared__ float o1s[HH1];
    const int b = blockIdx.x, t = threadIdx.x;
    float raw = out1_raw[b*HH1 + t] + fc_b1[t];
    o1s[t] = fmaxf(raw * (BN_SCALE * fbn1_g[t]) + fbn1_b[t], 0.f);
    __syncthreads();
    if (t < HH2) {
        float acc = fc_b2[t];
        #pragma unroll 4
        for (int j = 0; j < HH1; ++j) acc = fmaf(o1s[j], W2[j*HH2 + t], acc);
        float v2 = fmaxf(acc * (BN_SCALE * fbn2_g[t]) + fbn2_b[t], 0.f);
        float c = v2 * fc1_w[t];
        #pragma unroll
        for (int off = 32; off; off >>= 1) c += __shfl_down(c, off);
        if (t == 0) out[b] = c + fc1_b[0];
    }
}

extern "C" void kernel_launch(void* const* d_in, const int* in_sizes, int n_in,
                              void* d_out, int out_size, void* d_ws, size_t ws_size,
                              hipStream_t stream)
{
    const float* x      = (const float*)d_in[0];
    const int*   ei     = (const int*)  d_in[1];
    const float* ew     = (const float*)d_in[2];
    const float* w_root = (const float*)d_in[3];
    const float* w_rel  = (const float*)d_in[4];
    const float* b_rel  = (const float*)d_in[5];
    const float* ln_g   = (const float*)d_in[6];
    const float* ln_b   = (const float*)d_in[7];
    const float* gc1_w  = (const float*)d_in[8];
    const float* gc1_b  = (const float*)d_in[9];
    const float* bn1_g  = (const float*)d_in[10];
    const float* bn1_b  = (const float*)d_in[11];
    const float* gc2_w  = (const float*)d_in[12];
    const float* gc2_b  = (const float*)d_in[13];
    const float* bn2_g  = (const float*)d_in[14];
    const float* bn2_b  = (const float*)d_in[15];
    const float* fc_w1  = (const float*)d_in[16];
    const float* fc_b1  = (const float*)d_in[17];
    const float* fbn1_g = (const float*)d_in[18];
    const float* fbn1_b = (const float*)d_in[19];
    const float* fc_w2  = (const float*)d_in[20];
    const float* fc_b2  = (const float*)d_in[21];
    const float* fbn2_g = (const float*)d_in[22];
    const float* fbn2_b = (const float*)d_in[23];
    const float* fc1_w  = (const float*)d_in[24];
    const float* fc1_b  = (const float*)d_in[25];
    float* out = (float*)d_out;

    char* ws = (char*)d_ws;
    // layout: recs | stab | paggr (reused as o1p) | zbuf
    const size_t off_recs  = 0;                                   // 4096*4096*8 = 134,217,728
    const size_t off_stab  = off_recs + (size_t)NBLK*EPB*8;       // +2,097,152
    const size_t off_paggr = off_stab + (size_t)NBLK*NBK*2;
    const size_t o1p_sz    = (size_t)31*HH1*256*4;                // 8,126,464

    // pick largest rspl whose layout fits
    int rspl = 8;
    size_t pg_sz   = (size_t)rspl*NBK*NN*4;
    if (pg_sz < o1p_sz) pg_sz = o1p_sz;
    size_t off_zbuf = off_paggr + pg_sz;
    size_t need     = off_zbuf + (size_t)BB*KK1*4;
    if (ws_size < need) {
        rspl = 4;
        pg_sz = (size_t)rspl*NBK*NN*4;            // 9,039,872 >= o1p_sz
        off_zbuf = off_paggr + pg_sz;
        need = off_zbuf + (size_t)BB*KK1*4;       // 154.4 MB, proven
    }

    if (ws_size >= need) {
        uint2*          recs  = (uint2*)(ws + off_recs);
        unsigned short* stab  = (unsigned short*)(ws + off_stab);
        float*          paggr = (float*)(ws + off_paggr);
        float*          zbuf  = (float*)(ws + off_zbuf);
        float*          o1p   = (float*)(ws + off_paggr);  // reused after k_ln_conv

        k_place4<<<NBLK, TPB, 0, stream>>>(ei, ei + EE, ew, recs, stab);
        k_replay3<<<NBK*rspl, RTPB, 0, stream>>>(recs, stab, x, paggr, rspl);
        k_ln_conv<<<BB, 512, 0, stream>>>(x, paggr,
                                         w_root, w_rel, b_rel, ln_g, ln_b,
                                         gc1_w, gc1_b, bn1_g, bn1_b,
                                         gc2_w, gc2_b, bn2_g, bn2_b, zbuf, rspl);
        k_fc1_part<<<dim3(4,4,31), 256, 0, stream>>>(zbuf, fc_w1, o1p);
        k_tail_part<<<BB, 256, 0, stream>>>(o1p, fc_b1, fbn1_g, fbn1_b,
                                       fc_w2, fc_b2, fbn2_g, fbn2_b,
                                       fc1_w, fc1_b, out);
    } else {
        // round-1 fallback (proven <= 11.6 MB ws)
        float* agg      = (float*)(ws);
        float* zbuf     = (float*)(ws + 2259968);
        float* out1_raw = (float*)(ws + 2259968 + 9039872);

        hipMemsetAsync(agg,      0, (size_t)BB*NN*sizeof(float),  stream);
        hipMemsetAsync(out1_raw, 0, (size_t)BB*HH1*sizeof(float), stream);

        k_edge<<<EE/4/256, 256, 0, stream>>>(ei, ei + EE, ew, x, agg);
        k_sample<<<BB, 256, 0, stream>>>(x, agg, w_root, w_rel, b_rel, ln_g, ln_b,
                                         gc1_w, gc1_b, bn1_g, bn1_b,
                                         gc2_w, gc2_b, bn2_g, bn2_b, zbuf);
        k_fc1<<<dim3(4,4,31), 256, 0, stream>>>(zbuf, fc_w1, out1_raw);
        k_tail<<<BB, 256, 0, stream>>>(out1_raw, fc_b1, fbn1_g, fbn1_b,
                                       fc_w2, fc_b2, fbn2_g, fbn2_b,
                                       fc1_w, fc1_b, out);
    }
}

// Round 10
// 312.963 us; speedup vs baseline: 1.5840x; 1.0049x over previous
//
#include <hip/hip_runtime.h>
#include <hip/hip_bf16.h>

#define BB   256
#define NN   2207
#define MM   16
#define EE   16777216
#define CC1  12
#define CC2  4
#define HH1  256
#define HH2  64
#define KK1  (CC2*NN)          /* 8828 */
#define LN_EPS 1e-5f
#define BN_SCALE 0.9999950000374997f   /* 1/sqrt(1+1e-5) */
#define NBK  256               /* buckets == samples */
#define MAGIC 1946067ull       /* ceil(2^32/2207), exact for d < 564992 */
#define EPB  4096              /* edges per bin block */
#define TPB  512
#define EPT  (EPB/TPB)         /* 8 edges per thread */
#define NBLK (EE/EPB)          /* 4096 bin blocks */

static __device__ __forceinline__ unsigned bucket_of(int d) {
    return (unsigned)(((unsigned long long)(unsigned)d * MAGIC) >> 32);
}

// ===== PASS 1: rank + scan + DIRECT global scatter (no x-gather, no LDS staging) =====
// record = ( src<<12 | dst_local , w )  -- gather deferred to replay
__global__ __launch_bounds__(TPB, 8)
void k_place4(const int* __restrict__ src, const int* __restrict__ dst,
              const float* __restrict__ ew,
              uint2* __restrict__ recs, unsigned short* __restrict__ stab)
{
    __shared__ unsigned int hist[NBK], start[NBK];
    __shared__ unsigned int wtot[4];

    const int t = threadIdx.x;
    if (t < NBK) hist[t] = 0;
    __syncthreads();

    const int i4base = blockIdx.x * (EPB/4);
    unsigned key[EPT];           // (src<<12) | dst_local
    float    wv[EPT];
    unsigned short rk[EPT];      // intra-bucket rank < 4096
    unsigned char  bk[EPT];      // bucket
    #pragma unroll
    for (int q = 0; q < EPT/4; ++q) {
        int i4 = i4base + q*TPB + t;
        int4   s4 = reinterpret_cast<const int4*>(src)[i4];
        int4   d4 = reinterpret_cast<const int4*>(dst)[i4];
        float4 w4 = reinterpret_cast<const float4*>(ew)[i4];
        unsigned b0 = bucket_of(d4.x), b1 = bucket_of(d4.y);
        unsigned b2 = bucket_of(d4.z), b3 = bucket_of(d4.w);
        unsigned r0 = atomicAdd(&hist[b0], 1u);
        unsigned r1 = atomicAdd(&hist[b1], 1u);
        unsigned r2 = atomicAdd(&hist[b2], 1u);
        unsigned r3 = atomicAdd(&hist[b3], 1u);
        key[q*4+0] = ((unsigned)s4.x << 12) | (unsigned)(d4.x - (int)(b0*NN));
        key[q*4+1] = ((unsigned)s4.y << 12) | (unsigned)(d4.y - (int)(b1*NN));
        key[q*4+2] = ((unsigned)s4.z << 12) | (unsigned)(d4.z - (int)(b2*NN));
        key[q*4+3] = ((unsigned)s4.w << 12) | (unsigned)(d4.w - (int)(b3*NN));
        wv[q*4+0] = w4.x; wv[q*4+1] = w4.y; wv[q*4+2] = w4.z; wv[q*4+3] = w4.w;
        rk[q*4+0] = (unsigned short)r0; rk[q*4+1] = (unsigned short)r1;
        rk[q*4+2] = (unsigned short)r2; rk[q*4+3] = (unsigned short)r3;
        bk[q*4+0] = (unsigned char)b0; bk[q*4+1] = (unsigned char)b1;
        bk[q*4+2] = (unsigned char)b2; bk[q*4+3] = (unsigned char)b3;
    }
    __syncthreads();

    // exclusive prefix scan of hist[256] (4 waves of 64)
    if (t < NBK) {
        unsigned h = hist[t], v = h;
        #pragma unroll
        for (int off = 1; off < 64; off <<= 1) {
            unsigned u = __shfl_up(v, off);
            if ((t & 63) >= off) v += u;
        }
        start[t] = v - h;
        if ((t & 63) == 63) wtot[t >> 6] = v;
    }
    __syncthreads();
    if (t < NBK) {
        const int w = t >> 6;
        unsigned wo = 0;
        if (w > 0) wo += wtot[0];
        if (w > 1) wo += wtot[1];
        if (w > 2) wo += wtot[2];
        start[t] += wo;
        stab[blockIdx.x * NBK + t] = (unsigned short)(start[t]);
    }
    __syncthreads();

    // direct scatter to the block-private 32 KB region (L2 merges the 8B writes)
    uint2* rb = recs + (size_t)blockIdx.x * EPB;
    #pragma unroll
    for (int e = 0; e < EPT; ++e)
        rb[start[bk[e]] + (unsigned)rk[e]] =
            make_uint2(key[e], __float_as_uint(wv[e]));
}

// ===== PASS 2a: group-run replay, 32 groups, stab-prefetch pipeline =====
#define RTPB 512
__global__ __launch_bounds__(RTPB, 8)
void k_replay5(const uint2* __restrict__ recs, const unsigned short* __restrict__ stab,
               const float* __restrict__ x, float* __restrict__ paggr, int rspl)
{
    __shared__ float acc[NN];
    const int t = threadIdx.x;
    const int j = blockIdx.x & (NBK - 1);       // sample
    const int r = blockIdx.x >> 8;              // split index 0..rspl-1
    const int kpr = NBLK / rspl;                // bin-blocks per replay block
    for (int n = t; n < NN; n += RTPB) acc[n] = 0.f;
    __syncthreads();

    const int gid = t >> 4, l16 = t & 15;       // 32 groups of 16 lanes
    const int kb0 = r * kpr;
    const int niter = kpr >> 5;                 // kpr / 32 groups

    int kb = kb0 + gid;
    // prefetch first run bounds
    unsigned s0n = stab[(size_t)kb * NBK + j];
    unsigned s1n = (j < NBK-1) ? (unsigned)stab[(size_t)kb * NBK + j + 1]
                               : (unsigned)EPB;
    for (int i = 0; i < niter; ++i) {
        const unsigned s0 = s0n, s1 = s1n;
        const uint2* rp = recs + (size_t)kb * EPB;
        const int kbn = kb + 32;
        if (i + 1 < niter) {                    // prefetch next run bounds
            s0n = stab[(size_t)kbn * NBK + j];
            s1n = (j < NBK-1) ? (unsigned)stab[(size_t)kbn * NBK + j + 1]
                              : (unsigned)EPB;
        }
        for (unsigned u = s0 + (unsigned)l16; u < s1; u += 16u) {
            uint2 rec = rp[u];
            atomicAdd(&acc[rec.x & 0xFFFu],
                      x[rec.x >> 12] * __uint_as_float(rec.y));
        }
        kb = kbn;
    }
    __syncthreads();
    float* pa = paggr + ((size_t)r * NBK + j) * NN;
    for (int n = t; n < NN; n += RTPB) pa[n] = acc[n];
}

// ===== PASS 2b: sum partials + relu/LN/conv1/bn/conv2/bn -> z =====
__global__ __launch_bounds__(512)
void k_ln_conv(const float* __restrict__ x, const float* __restrict__ paggr,
              const float* __restrict__ w_root, const float* __restrict__ w_rel,
              const float* __restrict__ b_rel,
              const float* __restrict__ ln_g, const float* __restrict__ ln_b,
              const float* __restrict__ gc1_w, const float* __restrict__ gc1_b,
              const float* __restrict__ bn1_g, const float* __restrict__ bn1_b,
              const float* __restrict__ gc2_w, const float* __restrict__ gc2_b,
              const float* __restrict__ bn2_g, const float* __restrict__ bn2_b,
              float* __restrict__ z, int rspl)
{
    __shared__ float xs[NN], acc[NN];
    __shared__ float gw1[CC1*MM], gb1[CC1], sb1[CC1], tb1[CC1];
    __shared__ float gw2[CC2*CC1], gb2[CC2], sb2[CC2], tb2[CC2];
    __shared__ float redS[8], redQ[8];
    __shared__ float s_mu, s_rs;

    const int b = blockIdx.x, t = threadIdx.x;
    const float* xb = x + b*NN;
    for (int n = t; n < NN; n += 512) {
        xs[n] = xb[n];
        float a = 0.f;
        for (int r = 0; r < rspl; ++r)
            a += paggr[((size_t)r * NBK + b) * NN + n];
        acc[n] = a;
    }
    if (t < CC1*MM) gw1[t] = gc1_w[t];
    if (t >= 192 && t < 192+CC1) { int o = t-192; gb1[o]=gc1_b[o]; sb1[o]=BN_SCALE*bn1_g[o]; tb1[o]=bn1_b[o]; }
    if (t >= 208 && t < 208+CC2*CC1) gw2[t-208] = gc2_w[t-208];
    if (t >= 240 && t < 240+CC2) { int p=t-240; gb2[p]=gc2_b[p]; sb2[p]=BN_SCALE*bn2_g[p]; tb2[p]=bn2_b[p]; }

    float wr[MM], br[MM], wo[MM];
    #pragma unroll
    for (int m = 0; m < MM; ++m) { wr[m]=w_rel[m]; br[m]=b_rel[m]; wo[m]=w_root[m]; }
    __syncthreads();

    // LN statistics over (N, M)
    float S = 0.f, Q = 0.f;
    for (int n = t; n < NN; n += 512) {
        float a = acc[n], xv = xs[n];
        #pragma unroll
        for (int m = 0; m < MM; ++m) {
            float h = fmaxf(fmaf(a, wr[m], fmaf(xv, wo[m], br[m])), 0.f);
            S += h; Q += h*h;
        }
    }
    #pragma unroll
    for (int off = 32; off; off >>= 1) { S += __shfl_down(S, off); Q += __shfl_down(Q, off); }
    if ((t & 63) == 0) { redS[t>>6] = S; redQ[t>>6] = Q; }
    __syncthreads();
    if (t == 0) {
        float SS = 0.f, QQ = 0.f;
        #pragma unroll
        for (int i = 0; i < 8; ++i) { SS += redS[i]; QQ += redQ[i]; }
        const float inv = 1.f / (float)(NN*MM);
        float mu = SS * inv;
        float var = QQ * inv - mu*mu;
        s_mu = mu; s_rs = rsqrtf(var + LN_EPS);
    }
    __syncthreads();
    const float mu = s_mu, rs = s_rs;

    float* zb = z + (size_t)b * KK1;
    for (int n = t; n < NN; n += 512) {
        float a = acc[n], xv = xs[n];
        float hn[MM];
        const float4* g4  = reinterpret_cast<const float4*>(ln_g + n*MM);
        const float4* be4 = reinterpret_cast<const float4*>(ln_b + n*MM);
        #pragma unroll
        for (int q = 0; q < 4; ++q) {
            float4 g = g4[q], be = be4[q];
            float gg[4]  = {g.x, g.y, g.z, g.w};
            float bb_[4] = {be.x, be.y, be.z, be.w};
            #pragma unroll
            for (int j = 0; j < 4; ++j) {
                int m = q*4 + j;
                float h = fmaxf(fmaf(a, wr[m], fmaf(xv, wo[m], br[m])), 0.f);
                hn[m] = (h - mu) * rs * gg[j] + bb_[j];
            }
        }
        float y1[CC1];
        #pragma unroll
        for (int o = 0; o < CC1; ++o) {
            float a1 = gb1[o];
            #pragma unroll
            for (int m = 0; m < MM; ++m) a1 = fmaf(gw1[o*MM+m], hn[m], a1);
            y1[o] = fmaxf(a1, 0.f) * sb1[o] + tb1[o];
        }
        #pragma unroll
        for (int p = 0; p < CC2; ++p) {
            float a2 = gb2[p];
            #pragma unroll
            for (int o = 0; o < CC1; ++o) a2 = fmaf(gw2[p*CC1+o], y1[o], a2);
            zb[p*NN + n] = fmaxf(a2, 0.f) * sb2[p] + tb2[p];
        }
    }
}

// ------------- FC1 GEMM: split-K partials (no atomics) -------------
#define GK_CHUNK 288   /* grid.z = 31; 31*288 = 8928 >= 8828 */
__global__ __launch_bounds__(256)
void k_fc1_part(const float* __restrict__ z, const float* __restrict__ W1,
                float* __restrict__ out1_part)
{
    __shared__ float zs[64*36];
    __shared__ float ws_[32*68];
    const int bt = blockIdx.x, jt = blockIdx.y, ks = blockIdx.z;
    const int t = threadIdx.x;
    const int tb = t >> 4, tj = t & 15;
    const int k0 = ks * GK_CHUNK;
    const int kend = min(k0 + GK_CHUNK, KK1);
    float acc[4][4] = {};
    const int zrow = t >> 2, zcol = (t & 3) * 8;
    const int wrow = t >> 3, wcol = (t & 7) * 8;

    for (int kc = k0; kc < kend; kc += 32) {
        const float* zsrc = z + (size_t)(bt*64 + zrow)*KK1 + kc + zcol;
        #pragma unroll
        for (int q = 0; q < 2; ++q) {
            int k = kc + zcol + q*4;
            float4 v;
            if (k + 3 < kend) v = *reinterpret_cast<const float4*>(zsrc + q*4);
            else {
                v.x = (k+0 < kend) ? zsrc[q*4+0] : 0.f;
                v.y = (k+1 < kend) ? zsrc[q*4+1] : 0.f;
                v.z = (k+2 < kend) ? zsrc[q*4+2] : 0.f;
                v.w = (k+3 < kend) ? zsrc[q*4+3] : 0.f;
            }
            *reinterpret_cast<float4*>(&zs[zrow*36 + zcol + q*4]) = v;
        }
        {
            int k = kc + wrow;
            const float* wsrc = W1 + (size_t)k*HH1 + jt*64 + wcol;
            #pragma unroll
            for (int q = 0; q < 2; ++q) {
                float4 v;
                if (k < kend) v = *reinterpret_cast<const float4*>(wsrc + q*4);
                else v = float4{0.f,0.f,0.f,0.f};
                *reinterpret_cast<float4*>(&ws_[wrow*68 + wcol + q*4]) = v;
            }
        }
        __syncthreads();
        #pragma unroll
        for (int kk = 0; kk < 32; ++kk) {
            float4 w4 = *reinterpret_cast<const float4*>(&ws_[kk*68 + tj*4]);
            float zv[4], wv[4] = {w4.x, w4.y, w4.z, w4.w};
            #pragma unroll
            for (int ib = 0; ib < 4; ++ib) zv[ib] = zs[(tb*4+ib)*36 + kk];
            #pragma unroll
            for (int ib = 0; ib < 4; ++ib)
                #pragma unroll
                for (int ij = 0; ij < 4; ++ij)
                    acc[ib][ij] = fmaf(zv[ib], wv[ij], acc[ib][ij]);
        }
        __syncthreads();
    }
    #pragma unroll
    for (int ib = 0; ib < 4; ++ib) {
        int row = bt*64 + tb*4 + ib;
        float4 v = make_float4(acc[ib][0], acc[ib][1], acc[ib][2], acc[ib][3]);
        *reinterpret_cast<float4*>(
            &out1_part[((size_t)ks*256 + row)*HH1 + jt*64 + tj*4]) = v;
    }
}

// ------------- tail: sum partials -> bn-relu -> FC2 -> bn-relu -> dot -------------
__global__ __launch_bounds__(256)
void k_tail_part(const float* __restrict__ out1_part,
            const float* __restrict__ fc_b1, const float* __restrict__ fbn1_g,
            const float* __restrict__ fbn1_b,
            const float* __restrict__ W2, const float* __restrict__ fc_b2,
            const float* __restrict__ fbn2_g, const float* __restrict__ fbn2_b,
            const float* __restrict__ fc1_w, const float* __restrict__ fc1_b,
            float* __restrict__ out)
{
    __shared__ float o1s[HH1];
    const int b = blockIdx.x, t = threadIdx.x;
    float raw = fc_b1[t];
    #pragma unroll 4
    for (int ks = 0; ks < 31; ++ks)
        raw += out1_part[((size_t)ks*256 + b)*HH1 + t];
    o1s[t] = fmaxf(raw * (BN_SCALE * fbn1_g[t]) + fbn1_b[t], 0.f);
    __syncthreads();
    if (t < HH2) {
        float acc = fc_b2[t];
        #pragma unroll 4
        for (int j = 0; j < HH1; ++j) acc = fmaf(o1s[j], W2[j*HH2 + t], acc);
        float v2 = fmaxf(acc * (BN_SCALE * fbn2_g[t]) + fbn2_b[t], 0.f);
        float c = v2 * fc1_w[t];
        #pragma unroll
        for (int off = 32; off; off >>= 1) c += __shfl_down(c, off);
        if (t == 0) out[b] = c + fc1_b[0];
    }
}

// =================== fallback path (round-1, proven; used if ws too small) ===================
__global__ __launch_bounds__(256)
void k_edge(const int* __restrict__ src, const int* __restrict__ dst,
            const float* __restrict__ ew, const float* __restrict__ x,
            float* __restrict__ agg)
{
    int i = blockIdx.x * 256 + threadIdx.x;
    const int4   s4 = reinterpret_cast<const int4*>(src)[i];
    const int4   d4 = reinterpret_cast<const int4*>(dst)[i];
    const float4 w4 = reinterpret_cast<const float4*>(ew)[i];
    unsafeAtomicAdd(&agg[d4.x], x[s4.x] * w4.x);
    unsafeAtomicAdd(&agg[d4.y], x[s4.y] * w4.y);
    unsafeAtomicAdd(&agg[d4.z], x[s4.z] * w4.z);
    unsafeAtomicAdd(&agg[d4.w], x[s4.w] * w4.w);
}

__global__ __launch_bounds__(256)
void k_sample(const float* __restrict__ x, const float* __restrict__ agg,
              const float* __restrict__ w_root, const float* __restrict__ w_rel,
              const float* __restrict__ b_rel,
              const float* __restrict__ ln_g, const float* __restrict__ ln_b,
              const float* __restrict__ gc1_w, const float* __restrict__ gc1_b,
              const float* __restrict__ bn1_g, const float* __restrict__ bn1_b,
              const float* __restrict__ gc2_w, const float* __restrict__ gc2_b,
              const float* __restrict__ bn2_g, const float* __restrict__ bn2_b,
              float* __restrict__ z)
{
    __shared__ float xs[NN], as[NN];
    __shared__ float gw1[CC1*MM], gb1[CC1], sb1[CC1], tb1[CC1];
    __shared__ float gw2[CC2*CC1], gb2[CC2], sb2[CC2], tb2[CC2];
    __shared__ float redS[4], redQ[4];
    __shared__ float s_mu, s_rs;

    const int b = blockIdx.x, t = threadIdx.x;
    const float* xb = x + b*NN;
    const float* ab = agg + b*NN;
    for (int n = t; n < NN; n += 256) { xs[n] = xb[n]; as[n] = ab[n]; }
    if (t < CC1*MM) gw1[t] = gc1_w[t];
    if (t >= 192 && t < 192+CC1) { int o = t-192; gb1[o]=gc1_b[o]; sb1[o]=BN_SCALE*bn1_g[o]; tb1[o]=bn1_b[o]; }
    if (t >= 208 && t < 208+CC2*CC1) gw2[t-208] = gc2_w[t-208];
    if (t >= 240 && t < 240+CC2) { int p=t-240; gb2[p]=gc2_b[p]; sb2[p]=BN_SCALE*bn2_g[p]; tb2[p]=bn2_b[p]; }

    float wr[MM], br[MM], wo[MM];
    #pragma unroll
    for (int m = 0; m < MM; ++m) { wr[m]=w_rel[m]; br[m]=b_rel[m]; wo[m]=w_root[m]; }
    __syncthreads();

    float S = 0.f, Q = 0.f;
    for (int n = t; n < NN; n += 256) {
        float a = as[n], xv = xs[n];
        #pragma unroll
        for (int m = 0; m < MM; ++m) {
            float h = fmaxf(fmaf(a, wr[m], fmaf(xv, wo[m], br[m])), 0.f);
            S += h; Q += h*h;
        }
    }
    #pragma unroll
    for (int off = 32; off; off >>= 1) { S += __shfl_down(S, off); Q += __shfl_down(Q, off); }
    if ((t & 63) == 0) { redS[t>>6] = S; redQ[t>>6] = Q; }
    __syncthreads();
    if (t == 0) {
        float SS = redS[0]+redS[1]+redS[2]+redS[3];
        float QQ = redQ[0]+redQ[1]+redQ[2]+redQ[3];
        const float inv = 1.f / (float)(NN*MM);
        float mu = SS * inv;
        float var = QQ * inv - mu*mu;
        s_mu = mu; s_rs = rsqrtf(var + LN_EPS);
    }
    __syncthreads();
    const float mu = s_mu, rs = s_rs;

    float* zb = z + (size_t)b * KK1;
    for (int n = t; n < NN; n += 256) {
        float a = as[n], xv = xs[n];
        float hn[MM];
        const float4* g4  = reinterpret_cast<const float4*>(ln_g + n*MM);
        const float4* be4 = reinterpret_cast<const float4*>(ln_b + n*MM);
        #pragma unroll
        for (int q = 0; q < 4; ++q) {
            float4 g = g4[q], be = be4[q];
            float gg[4]  = {g.x, g.y, g.z, g.w};
            float bb_[4] = {be.x, be.y, be.z, be.w};
            #pragma unroll
            for (int j = 0; j < 4; ++j) {
                int m = q*4 + j;
                float h = fmaxf(fmaf(a, wr[m], fmaf(xv, wo[m], br[m])), 0.f);
                hn[m] = (h - mu) * rs * gg[j] + bb_[j];
            }
        }
        float y1[CC1];
        #pragma unroll
        for (int o = 0; o < CC1; ++o) {
            float a1 = gb1[o];
            #pragma unroll
            for (int m = 0; m < MM; ++m) a1 = fmaf(gw1[o*MM+m], hn[m], a1);
            y1[o] = fmaxf(a1, 0.f) * sb1[o] + tb1[o];
        }
        #pragma unroll
        for (int p = 0; p < CC2; ++p) {
            float a2 = gb2[p];
            #pragma unroll
            for (int o = 0; o < CC1; ++o) a2 = fmaf(gw2[p*CC1+o], y1[o], a2);
            zb[p*NN + n] = fmaxf(a2, 0.f) * sb2[p] + tb2[p];
        }
    }
}

__global__ __launch_bounds__(256)
void k_fc1(const float* __restrict__ z, const float* __restrict__ W1,
           float* __restrict__ out1_raw)
{
    __shared__ float zs[64*36];
    __shared__ float ws_[32*68];
    const int bt = blockIdx.x, jt = blockIdx.y, ks = blockIdx.z;
    const int t = threadIdx.x;
    const int tb = t >> 4, tj = t & 15;
    const int k0 = ks * GK_CHUNK;
    const int kend = min(k0 + GK_CHUNK, KK1);
    float acc[4][4] = {};
    const int zrow = t >> 2, zcol = (t & 3) * 8;
    const int wrow = t >> 3, wcol = (t & 7) * 8;

    for (int kc = k0; kc < kend; kc += 32) {
        const float* zsrc = z + (size_t)(bt*64 + zrow)*KK1 + kc + zcol;
        #pragma unroll
        for (int q = 0; q < 2; ++q) {
            int k = kc + zcol + q*4;
            float4 v;
            if (k + 3 < kend) v = *reinterpret_cast<const float4*>(zsrc + q*4);
            else {
                v.x = (k+0 < kend) ? zsrc[q*4+0] : 0.f;
                v.y = (k+1 < kend) ? zsrc[q*4+1] : 0.f;
                v.z = (k+2 < kend) ? zsrc[q*4+2] : 0.f;
                v.w = (k+3 < kend) ? zsrc[q*4+3] : 0.f;
            }
            *reinterpret_cast<float4*>(&zs[zrow*36 + zcol + q*4]) = v;
        }
        {
            int k = kc + wrow;
            const float* wsrc = W1 + (size_t)k*HH1 + jt*64 + wcol;
            #pragma unroll
            for (int q = 0; q < 2; ++q) {
                float4 v;
                if (k < kend) v = *reinterpret_cast<const float4*>(wsrc + q*4);
                else v = float4{0.f,0.f,0.f,0.f};
                *reinterpret_cast<float4*>(&ws_[wrow*68 + wcol + q*4]) = v;
            }
        }
        __syncthreads();
        #pragma unroll
        for (int kk = 0; kk < 32; ++kk) {
            float4 w4 = *reinterpret_cast<const float4*>(&ws_[kk*68 + tj*4]);
            float zv[4], wv[4] = {w4.x, w4.y, w4.z, w4.w};
            #pragma unroll
            for (int ib = 0; ib < 4; ++ib) zv[ib] = zs[(tb*4+ib)*36 + kk];
            #pragma unroll
            for (int ib = 0; ib < 4; ++ib)
                #pragma unroll
                for (int ij = 0; ij < 4; ++ij)
                    acc[ib][ij] = fmaf(zv[ib], wv[ij], acc[ib][ij]);
        }
        __syncthreads();
    }
    #pragma unroll
    for (int ib = 0; ib < 4; ++ib) {
        int row = bt*64 + tb*4 + ib;
        #pragma unroll
        for (int ij = 0; ij < 4; ++ij)
            unsafeAtomicAdd(&out1_raw[row*HH1 + jt*64 + tj*4 + ij], acc[ib][ij]);
    }
}

__global__ __launch_bounds__(256)
void k_tail(const float* __restrict__ out1_raw,
            const float* __restrict__ fc_b1, const float* __restrict__ fbn1_g,
            const float* __restrict__ fbn1_b,
            const float* __restrict__ W2, const float* __restrict__ fc_b2,
            const float* __restrict__ fbn2_g, const float* __restrict__ fbn2_b,
            const float* __restrict__ fc1_w, const float* __restrict__ fc1_b,
            float* __restrict__ out)
{
    __shared__ float o1s[HH1];
    const int b = blockIdx.x, t = threadIdx.x;
    float raw = out1_raw[b*HH1 + t] + fc_b1[t];
    o1s[t] = fmaxf(raw * (BN_SCALE * fbn1_g[t]) + fbn1_b[t], 0.f);
    __syncthreads();
    if (t < HH2) {
        float acc = fc_b2[t];
        #pragma unroll 4
        for (int j = 0; j < HH1; ++j) acc = fmaf(o1s[j], W2[j*HH2 + t], acc);
        float v2 = fmaxf(acc * (BN_SCALE * fbn2_g[t]) + fbn2_b[t], 0.f);
        float c = v2 * fc1_w[t];
        #pragma unroll
        for (int off = 32; off; off >>= 1) c += __shfl_down(c, off);
        if (t == 0) out[b] = c + fc1_b[0];
    }
}

extern "C" void kernel_launch(void* const* d_in, const int* in_sizes, int n_in,
                              void* d_out, int out_size, void* d_ws, size_t ws_size,
                              hipStream_t stream)
{
    const float* x      = (const float*)d_in[0];
    const int*   ei     = (const int*)  d_in[1];
    const float* ew     = (const float*)d_in[2];
    const float* w_root = (const float*)d_in[3];
    const float* w_rel  = (const float*)d_in[4];
    const float* b_rel  = (const float*)d_in[5];
    const float* ln_g   = (const float*)d_in[6];
    const float* ln_b   = (const float*)d_in[7];
    const float* gc1_w  = (const float*)d_in[8];
    const float* gc1_b  = (const float*)d_in[9];
    const float* bn1_g  = (const float*)d_in[10];
    const float* bn1_b  = (const float*)d_in[11];
    const float* gc2_w  = (const float*)d_in[12];
    const float* gc2_b  = (const float*)d_in[13];
    const float* bn2_g  = (const float*)d_in[14];
    const float* bn2_b  = (const float*)d_in[15];
    const float* fc_w1  = (const float*)d_in[16];
    const float* fc_b1  = (const float*)d_in[17];
    const float* fbn1_g = (const float*)d_in[18];
    const float* fbn1_b = (const float*)d_in[19];
    const float* fc_w2  = (const float*)d_in[20];
    const float* fc_b2  = (const float*)d_in[21];
    const float* fbn2_g = (const float*)d_in[22];
    const float* fbn2_b = (const float*)d_in[23];
    const float* fc1_w  = (const float*)d_in[24];
    const float* fc1_b  = (const float*)d_in[25];
    float* out = (float*)d_out;

    char* ws = (char*)d_ws;
    // layout: recs | stab | paggr (reused as o1p) | zbuf
    const size_t off_recs  = 0;                                   // 4096*4096*8 = 134,217,728
    const size_t off_stab  = off_recs + (size_t)NBLK*EPB*8;       // +2,097,152
    const size_t off_paggr = off_stab + (size_t)NBLK*NBK*2;
    const size_t o1p_sz    = (size_t)31*HH1*256*4;                // 8,126,464

    // pick largest rspl whose layout fits
    int rspl = 8;
    size_t pg_sz   = (size_t)rspl*NBK*NN*4;
    if (pg_sz < o1p_sz) pg_sz = o1p_sz;
    size_t off_zbuf = off_paggr + pg_sz;
    size_t need     = off_zbuf + (size_t)BB*KK1*4;
    if (ws_size < need) {
        rspl = 4;
        pg_sz = (size_t)rspl*NBK*NN*4;            // 9,039,872 >= o1p_sz
        off_zbuf = off_paggr + pg_sz;
        need = off_zbuf + (size_t)BB*KK1*4;       // 154.4 MB, proven
    }

    if (ws_size >= need) {
        uint2*          recs  = (uint2*)(ws + off_recs);
        unsigned short* stab  = (unsigned short*)(ws + off_stab);
        float*          paggr = (float*)(ws + off_paggr);
        float*          zbuf  = (float*)(ws + off_zbuf);
        float*          o1p   = (float*)(ws + off_paggr);  // reused after k_ln_conv

        k_place4<<<NBLK, TPB, 0, stream>>>(ei, ei + EE, ew, recs, stab);
        k_replay5<<<NBK*rspl, RTPB, 0, stream>>>(recs, stab, x, paggr, rspl);
        k_ln_conv<<<BB, 512, 0, stream>>>(x, paggr,
                                         w_root, w_rel, b_rel, ln_g, ln_b,
                                         gc1_w, gc1_b, bn1_g, bn1_b,
                                         gc2_w, gc2_b, bn2_g, bn2_b, zbuf, rspl);
        k_fc1_part<<<dim3(4,4,31), 256, 0, stream>>>(zbuf, fc_w1, o1p);
        k_tail_part<<<BB, 256, 0, stream>>>(o1p, fc_b1, fbn1_g, fbn1_b,
                                       fc_w2, fc_b2, fbn2_g, fbn2_b,
                                       fc1_w, fc1_b, out);
    } else {
        // round-1 fallback (proven <= 11.6 MB ws)
        float* agg      = (float*)(ws);
        float* zbuf     = (float*)(ws + 2259968);
        float* out1_raw = (float*)(ws + 2259968 + 9039872);

        hipMemsetAsync(agg,      0, (size_t)BB*NN*sizeof(float),  stream);
        hipMemsetAsync(out1_raw, 0, (size_t)BB*HH1*sizeof(float), stream);

        k_edge<<<EE/4/256, 256, 0, stream>>>(ei, ei + EE, ew, x, agg);
        k_sample<<<BB, 256, 0, stream>>>(x, agg, w_root, w_rel, b_rel, ln_g, ln_b,
                                         gc1_w, gc1_b, bn1_g, bn1_b,
                                         gc2_w, gc2_b, bn2_g, bn2_b, zbuf);
        k_fc1<<<dim3(4,4,31), 256, 0, stream>>>(zbuf, fc_w1, out1_raw);
        k_tail<<<BB, 256, 0, stream>>>(out1_raw, fc_b1, fbn1_g, fbn1_b,
                                       fc_w2, fc_b2, fbn2_g, fbn2_b,
                                       fc1_w, fc1_b, out);
    }
}